// Round 3
// baseline (1112.905 us; speedup 1.0000x reference)
//
#include <hip/hip_runtime.h>
#include <hip/hip_fp16.h>
#include <cstddef>

#define Wn 12
#define Nn 20000
#define Cn 64
#define En 320000
#define OFFS_STRIDE 20032

typedef _Float16 h4v __attribute__((ext_vector_type(4)));
typedef _Float16 h8v __attribute__((ext_vector_type(8)));
typedef float    f4v __attribute__((ext_vector_type(4)));
typedef float    f2v __attribute__((ext_vector_type(2)));

__device__ __forceinline__ float elu_f(float v) {
    return v > 0.f ? v : (expf(v) - 1.f);
}

// ---------------------------------------------------------------------------
// Weight prep: pack all 4 kernel sizes (sig+gate) into MFMA B-fragment order.
// Layout (halfs): groups g=0..3 at bases {0,2048,8192,18432}; within a group:
//   [sg in {sig,gate}][s = (dw+g)*2 + ic_half][lane 0..63][j 0..7]
// where the 8 halfs at (lane,j) are B[k][col]: col = lane&15 (oc in group),
// k = (lane>>4)*8 + j within the 32-slice, ic = ic_half*32 + k, t = dw+g.
// One ds_read_b128 per B fragment in the main kernel, bank-linear.
// ---------------------------------------------------------------------------
__global__ __launch_bounds__(256) void wprep_kernel(
    const float* __restrict__ sw1, const float* __restrict__ gw1,
    const float* __restrict__ sw3, const float* __restrict__ gw3,
    const float* __restrict__ sw5, const float* __restrict__ gw5,
    const float* __restrict__ sw7, const float* __restrict__ gw7,
    __half* __restrict__ dst)
{
    const int i = blockIdx.x * 256 + threadIdx.x;   // 32768 total
    if (i >= 32768) return;
    const int j    = i & 7;
    const int lane = (i >> 3) & 63;
    const int slot = i >> 9;                        // 0..63
    int g, loc;
    if (slot < 4)       { g = 0; loc = slot; }
    else if (slot < 16) { g = 1; loc = slot - 4; }
    else if (slot < 36) { g = 2; loc = slot - 16; }
    else                { g = 3; loc = slot - 36; }
    const int k   = 2 * g + 1;
    const int nks = 2 * k;                          // k-steps per path
    const int sg  = (loc >= nks) ? 1 : 0;          // 0 = sig, 1 = gate
    const int s   = loc - sg * nks;
    const int t   = s >> 1;                         // tap 0..k-1
    const int ih  = s & 1;                          // ic half
    const int oc  = lane & 15;
    const int ic  = ih * 32 + (lane >> 4) * 8 + j;
    const float* src;
    switch (g * 2 + sg) {
      case 0: src = sw1; break; case 1: src = gw1; break;
      case 2: src = sw3; break; case 3: src = gw3; break;
      case 4: src = sw5; break; case 5: src = gw5; break;
      case 6: src = sw7; break; default: src = gw7; break;
    }
    dst[i] = __float2half(src[(oc * 64 + ic) * k + t]);
}

// ---------------------------------------------------------------------------
// One oc-group of the inception conv via MFMA. 4 waves; wave wv owns windows
// w = wv*3 + {0,1,2}. Per (dw, ic_half): 2 B-frag loads (sig,gate) + 3 A-frag
// loads + 6 independent MFMAs (no dependent-chain stalls even at 1 wave/SIMD).
// Boundary windows skip out-of-range dw (wave-uniform branch).
// ---------------------------------------------------------------------------
template<int G>
__device__ __forceinline__ void mfma_group(
    const __half* __restrict__ wTg,    // global fragment-packed weights, group G
    __half* __restrict__ wsh,
    const __half* __restrict__ xsh,
    const float* __restrict__ sb, const float* __restrict__ gb,
    float* __restrict__ h, int nb, int tid)
{
    constexpr int NKS = 2 * (2 * G + 1);
    // stage this group's fragments: (2G+1)*4096 B, contiguous copy
    {
        const uint4* src = (const uint4*)wTg;
        uint4* dst = (uint4*)wsh;
        #pragma unroll
        for (int i = 0; i < 2 * G + 1; ++i)
            dst[tid + i * 256] = src[tid + i * 256];
    }
    __syncthreads();

    const int lane = tid & 63;
    const int wv   = tid >> 6;                 // 0..3
    const int node16 = lane & 15;
    // lane-dependent part of the A-frag LDS byte offset, per ic-half
    const int abase = node16 * 128;
    const int swz   = (lane & 7) << 4;
    const int aoff0 = abase + ((0  + (lane >> 4) * 16) ^ swz);
    const int aoff1 = abase + ((64 + (lane >> 4) * 16) ^ swz);

    f4v accS[3], accG[3];
    #pragma unroll
    for (int m = 0; m < 3; ++m) {
        accS[m] = (f4v){0.f, 0.f, 0.f, 0.f};
        accG[m] = (f4v){0.f, 0.f, 0.f, 0.f};
    }

    #pragma unroll
    for (int s2 = 0; s2 < 2 * G + 1; ++s2) {   // dw = s2 - G
        const int dw = s2 - G;
        #pragma unroll
        for (int ih = 0; ih < 2; ++ih) {
            const int s = s2 * 2 + ih;
            const h8v bs = *(const h8v*)&wsh[(s * 64 + lane) * 8];
            const h8v bg = *(const h8v*)&wsh[((NKS + s) * 64 + lane) * 8];
            const int laneoff = ih ? aoff1 : aoff0;
            #pragma unroll
            for (int m = 0; m < 3; ++m) {
                const int w  = wv * 3 + m;
                const int wp = w + dw;
                if (wp >= 0 && wp < Wn) {      // wave-uniform
                    const h8v a = *(const h8v*)((const char*)xsh + wp * 2048 + laneoff);
                    accS[m] = __builtin_amdgcn_mfma_f32_16x16x32_f16(a, bs, accS[m], 0, 0, 0);
                    accG[m] = __builtin_amdgcn_mfma_f32_16x16x32_f16(a, bg, accG[m], 0, 0, 0);
                }
            }
        }
    }

    // epilogue: D layout col = lane&15 (oc), row = (lane>>4)*4 + r (node)
    const float sbv = sb[node16];
    const float gbv = gb[node16];
    const int oc = G * 16 + node16;
    #pragma unroll
    for (int m = 0; m < 3; ++m) {
        const int w = wv * 3 + m;
        #pragma unroll
        for (int r = 0; r < 4; ++r) {
            const int node = (lane >> 4) * 4 + r;
            const float sv = accS[m][r] + sbv;
            const float gv = accG[m][r] + gbv;
            const float rv = sv > 0.f ? sv : 0.f;
            const float sg = 1.f / (1.f + expf(-gv));
            h[((size_t)w * Nn + nb + node) * Cn + oc] = rv * sg;
        }
    }
    __syncthreads();   // wsh reused by next group
}

// ---------------------------------------------------------------------------
// Inception gated temporal conv, MFMA version. Block = 16 nodes x all 12 w.
// x staged once as fp16 in LDS with XOR swizzle (granule ^= (node&7)<<4) --
// the [node][128B] row layout is otherwise a 16-way bank conflict on the
// 16-lane A-fragment read. LDS 53.2 KB -> 3 blocks/CU.
// ---------------------------------------------------------------------------
__global__ __launch_bounds__(256, 3) void inception_mfma_kernel(
    const float* __restrict__ x,
    const float* __restrict__ sb1, const float* __restrict__ gb1,
    const float* __restrict__ sb3, const float* __restrict__ gb3,
    const float* __restrict__ sb5, const float* __restrict__ gb5,
    const float* __restrict__ sb7, const float* __restrict__ gb7,
    const __half* __restrict__ wT,
    float* __restrict__ h)
{
    __shared__ __align__(16) __half xsh[12 * 16 * 64];   // 24,576 B
    __shared__ __align__(16) __half wsh[14336];           // 28,672 B (max group)
    const int tid = threadIdx.x;
    const int nb  = blockIdx.x * 16;

    const float4* xg = (const float4*)x;
    for (int i = tid; i < 3072; i += 256) {
        const int w = i >> 8, r = i & 255, node = r >> 4, c4 = r & 15;
        const float4 v = xg[((size_t)w * Nn + nb + node) * 16 + c4];
        h4v p = { (_Float16)v.x, (_Float16)v.y, (_Float16)v.z, (_Float16)v.w };
        const int off = w * 2048 + node * 128 + (((c4 << 3)) ^ ((node & 7) << 4));
        *(h4v*)((char*)xsh + off) = p;
    }
    // first __syncthreads inside mfma_group<0> covers x staging too
    mfma_group<0>(wT,         wsh, xsh, sb1, gb1, h, nb, tid);
    mfma_group<1>(wT + 2048,  wsh, xsh, sb3, gb3, h, nb, tid);
    mfma_group<2>(wT + 8192,  wsh, xsh, sb5, gb5, h, nb, tid);
    mfma_group<3>(wT + 18432, wsh, xsh, sb7, gb7, h, nb, tid);
}

// ---------------------------------------------------------------------------
// Per-window (N x 64) @ (64 x 64) matmul, fp32 in -> fp16 out. Tail guarded.
// ---------------------------------------------------------------------------
__global__ __launch_bounds__(256) void matmul_half_kernel(
    const float* __restrict__ h, const float* __restrict__ gw,
    __half* __restrict__ t)
{
    const int w  = blockIdx.y;
    const int nb = blockIdx.x * 64;
    __shared__ float wm[64 * 64];
    __shared__ float hT[64 * 64];
    const int tid = threadIdx.x;

    const float4* wsrc = (const float4*)(gw + (size_t)w * 4096);
    float4* wm4 = (float4*)wm;
    for (int i = tid; i < 1024; i += 256) wm4[i] = wsrc[i];

    {
        const int n = tid >> 2, icq = tid & 3;
        const int nclamp = (nb + n < Nn) ? (nb + n) : (Nn - 1);
        const float4* hsrc = (const float4*)(h + ((size_t)w * Nn + nclamp) * 64);
        #pragma unroll
        for (int k = 0; k < 4; ++k) {
            float4 v = hsrc[icq + 4 * k];
            int ic = (icq + 4 * k) * 4;
            hT[(ic + 0) * 64 + n] = v.x;
            hT[(ic + 1) * 64 + n] = v.y;
            hT[(ic + 2) * 64 + n] = v.z;
            hT[(ic + 3) * 64 + n] = v.w;
        }
    }
    __syncthreads();

    const int oc0 = (tid & 15) * 4;
    const int n0  = (tid >> 4) * 4;
    float acc[4][4] = {{0.f}};
    #pragma unroll
    for (int ic = 0; ic < 64; ++ic) {
        const float4 hv = *(const float4*)&hT[ic * 64 + n0];
        const float4 wv = *(const float4*)&wm[ic * 64 + oc0];
        acc[0][0] = fmaf(hv.x, wv.x, acc[0][0]);
        acc[0][1] = fmaf(hv.x, wv.y, acc[0][1]);
        acc[0][2] = fmaf(hv.x, wv.z, acc[0][2]);
        acc[0][3] = fmaf(hv.x, wv.w, acc[0][3]);
        acc[1][0] = fmaf(hv.y, wv.x, acc[1][0]);
        acc[1][1] = fmaf(hv.y, wv.y, acc[1][1]);
        acc[1][2] = fmaf(hv.y, wv.z, acc[1][2]);
        acc[1][3] = fmaf(hv.y, wv.w, acc[1][3]);
        acc[2][0] = fmaf(hv.z, wv.x, acc[2][0]);
        acc[2][1] = fmaf(hv.z, wv.y, acc[2][1]);
        acc[2][2] = fmaf(hv.z, wv.z, acc[2][2]);
        acc[2][3] = fmaf(hv.z, wv.w, acc[2][3]);
        acc[3][0] = fmaf(hv.w, wv.x, acc[3][0]);
        acc[3][1] = fmaf(hv.w, wv.y, acc[3][1]);
        acc[3][2] = fmaf(hv.w, wv.z, acc[3][2]);
        acc[3][3] = fmaf(hv.w, wv.w, acc[3][3]);
    }

    #pragma unroll
    for (int i = 0; i < 4; ++i) {
        if (nb + n0 + i < Nn) {
            __half2 lo = __floats2half2_rn(acc[i][0], acc[i][1]);
            __half2 hi = __floats2half2_rn(acc[i][2], acc[i][3]);
            uint2 pack;
            pack.x = *(const unsigned int*)&lo;
            pack.y = *(const unsigned int*)&hi;
            *(uint2*)&t[((size_t)w * Nn + nb + n0 + i) * 64 + oc0] = pack;
        }
    }
}

// ---------------------------------------------------------------------------
// Counting-sort preamble.
// ---------------------------------------------------------------------------
__global__ __launch_bounds__(256) void hist_kernel(
    const int* __restrict__ ei, int* __restrict__ deg)
{
    const int w = blockIdx.y;
    const int e = blockIdx.x * 256 + threadIdx.x;
    const int dst = __builtin_nontemporal_load(ei + (size_t)w * 2 * En + En + e);
    atomicAdd(&deg[w * Nn + dst], 1);
}

// 12 blocks x 1024 threads: hierarchical scan (was 12 waves on the whole GPU).
__global__ __launch_bounds__(1024) void scan_kernel(
    const int* __restrict__ deg, int* __restrict__ offs, int* __restrict__ curs)
{
    const int w   = blockIdx.x;
    const int tid = threadIdx.x;
    const int lane = tid & 63;
    const int wv   = tid >> 6;            // 0..15
    __shared__ int wsum[16];
    __shared__ int ctot;
    int running = 0;
    for (int base = 0; base < Nn; base += 1024) {
        const int i = base + tid;
        int v = (i < Nn) ? deg[w * Nn + i] : 0;
        int sum = v;
        #pragma unroll
        for (int d = 1; d < 64; d <<= 1) {
            int t = __shfl_up(sum, d);
            if (lane >= d) sum += t;
        }
        if (lane == 63) wsum[wv] = sum;
        __syncthreads();
        if (tid < 16) {
            int orig = wsum[tid];
            int s = orig;
            #pragma unroll
            for (int d = 1; d < 16; d <<= 1) {
                int t = __shfl_up(s, d);
                if (tid >= d) s += t;
            }
            wsum[tid] = s - orig;         // exclusive across waves
            if (tid == 15) ctot = s;
        }
        __syncthreads();
        if (i < Nn) {
            const int e = running + wsum[wv] + (sum - v);
            offs[w * OFFS_STRIDE + i] = e;
            curs[w * Nn + i] = e;
        }
        running += ctot;
        __syncthreads();
    }
    if (tid == 0) offs[w * OFFS_STRIDE + Nn] = running;
}

// ---------------------------------------------------------------------------
// Counting-sort scatter. XCD-affinity swizzle: all blocks of window w share
// b%8 -> the window's 2.56 MB pairs region lives in one XCD's L2.
// v2: 5 edges per thread (independent atomic->store chains in flight) and
// NONTEMPORAL loads for the read-once ei/ew streams so they don't evict the
// scatter working set from L2 (theory: the 8x write amplification in round-1
// counters was stream-eviction of partially-filled scatter lines).
// ---------------------------------------------------------------------------
__global__ __launch_bounds__(256) void sortpairs_kernel(
    const int* __restrict__ ei, const float* __restrict__ ew,
    int* __restrict__ curs, float2* __restrict__ pairs)
{
    const int b = blockIdx.x;             // 3000 blocks, 1280 edges each
    const int r = b & 7, q = b >> 3;
    int w, eg;
    if (q < 250) { w = r; eg = q; }
    else { int q2 = q - 250; w = 8 + (r >> 1); eg = q2 * 2 + (r & 1); }
    const int base = eg * 1280 + threadIdx.x;
    const int* eis = ei + (size_t)w * 2 * En;
    const float* ews = ew + (size_t)w * En;

    int src[5], dst[5];
    float wt[5];
    #pragma unroll
    for (int it = 0; it < 5; ++it) {
        const int e = base + it * 256;
        src[it] = __builtin_nontemporal_load(eis + e);
        dst[it] = __builtin_nontemporal_load(eis + En + e);
        wt[it]  = __builtin_nontemporal_load(ews + e);
    }
    int pos[5];
    #pragma unroll
    for (int it = 0; it < 5; ++it)
        pos[it] = atomicAdd(&curs[w * Nn + dst[it]], 1);
    float2* pw = pairs + (size_t)w * En;
    #pragma unroll
    for (int it = 0; it < 5; ++it)
        pw[pos[it]] = make_float2(__int_as_float(src[it]), wt[it]);
}

// ---------------------------------------------------------------------------
// Aggregation: one wave per dst; 2 edges in flight (32 lanes x __half2 each,
// 128 B/edge in half the instructions). XCD-affinity swizzle: blocks of
// window w land on b%8=f(w) -> each XCD's L2 holds <=2 t-slabs (5 MB) instead
// of all 12 (31 MB thrash). v2: pairs/x are read-once -> nontemporal loads;
// out is written-once -> nontemporal store. Keeps L2 reserved for the hot
// t-slab gather.
// ---------------------------------------------------------------------------
template<bool LAST>
__global__ __launch_bounds__(256) void agg_kernel(
    const __half* __restrict__ t, const float2* __restrict__ pairs,
    const int* __restrict__ offs, const float* __restrict__ b,
    const float* __restrict__ x, float* __restrict__ out)
{
    const int blk = blockIdx.x;
    const int r = blk & 7, q = blk >> 3;
    int w, ng;
    if (q < 5000) { w = r; ng = q; }
    else { int q2 = q - 5000; w = 8 + (r >> 1); ng = q2 * 2 + (r & 1); }

    const int d    = ng * 4 + (threadIdx.x >> 6);
    const int lane = threadIdx.x & 63;
    const int hgrp = lane >> 5;           // which of 2 concurrent edges
    const int c    = lane & 31;           // channel pair index
    const int* ow  = offs + w * OFFS_STRIDE;
    const int beg = ow[d];
    const int end = ow[d + 1];
    const f2v* pw = (const f2v*)(pairs + (size_t)w * En);
    const __half* tw = t + (size_t)w * Nn * Cn;

    float ax = 0.f, ay = 0.f;
    int i = beg;
    for (; i + 4 <= end; i += 4) {
        f2v p0 = __builtin_nontemporal_load(pw + i + hgrp);
        f2v p1 = __builtin_nontemporal_load(pw + i + 2 + hgrp);
        float2 f0 = __half22float2(*(const __half2*)&tw[(size_t)__float_as_int(p0.x) * Cn + 2 * c]);
        float2 f1 = __half22float2(*(const __half2*)&tw[(size_t)__float_as_int(p1.x) * Cn + 2 * c]);
        ax = fmaf(p0.y, f0.x, ax);
        ay = fmaf(p0.y, f0.y, ay);
        ax = fmaf(p1.y, f1.x, ax);
        ay = fmaf(p1.y, f1.y, ay);
    }
    if (i + 2 <= end) {
        f2v p0 = __builtin_nontemporal_load(pw + i + hgrp);
        float2 f0 = __half22float2(*(const __half2*)&tw[(size_t)__float_as_int(p0.x) * Cn + 2 * c]);
        ax = fmaf(p0.y, f0.x, ax);
        ay = fmaf(p0.y, f0.y, ay);
        i += 2;
    }
    if (i < end && hgrp == 0) {
        f2v p0 = __builtin_nontemporal_load(pw + i);
        float2 f0 = __half22float2(*(const __half2*)&tw[(size_t)__float_as_int(p0.x) * Cn + 2 * c]);
        ax = fmaf(p0.y, f0.x, ax);
        ay = fmaf(p0.y, f0.y, ay);
    }

    ax += __shfl_xor(ax, 32);
    ay += __shfl_xor(ay, 32);

    if (hgrp == 0) {
        const float2 bv = *(const float2*)&b[w * Cn + 2 * c];
        float vx = elu_f(ax + bv.x);
        float vy = elu_f(ay + bv.y);
        const size_t oi = ((size_t)w * Nn + d) * Cn + 2 * c;
        if (LAST) {
            const f2v xv = __builtin_nontemporal_load((const f2v*)&x[oi]);
            vx += xv.x;
            vy += xv.y;
        }
        f2v res = { vx, vy };
        __builtin_nontemporal_store(res, (f2v*)&out[oi]);
    }
}

// ---------------------------------------------------------------------------
// ws layout (floats):
//   [0)          pairs : 7,680,000
//   [7,680,000)  offs  :   240,384 (int)
//   [7,920,384)  curs  :   240,000 (int)
//   [8,160,384)  deg   :   240,000 (int)  -- reused as wT (32768 halfs) after scan
//   [8,400,384)  H     : 15,360,000
// t (fp16) lives in d_out between matmul and agg; final result built in H,
// then copied to d_out.
// ---------------------------------------------------------------------------
extern "C" void kernel_launch(void* const* d_in, const int* in_sizes, int n_in,
                              void* d_out, int out_size, void* d_ws, size_t ws_size,
                              hipStream_t stream)
{
    const float* x    = (const float*)d_in[0];
    const int*   ei   = (const int*)d_in[1];
    const float* ew   = (const float*)d_in[2];
    const float* sw1  = (const float*)d_in[3];
    const float* sb1  = (const float*)d_in[4];
    const float* gw1  = (const float*)d_in[5];
    const float* gb1  = (const float*)d_in[6];
    const float* sw3  = (const float*)d_in[7];
    const float* sb3  = (const float*)d_in[8];
    const float* gw3  = (const float*)d_in[9];
    const float* gb3  = (const float*)d_in[10];
    const float* sw5  = (const float*)d_in[11];
    const float* sb5  = (const float*)d_in[12];
    const float* gw5  = (const float*)d_in[13];
    const float* gb5  = (const float*)d_in[14];
    const float* sw7  = (const float*)d_in[15];
    const float* sb7  = (const float*)d_in[16];
    const float* gw7  = (const float*)d_in[17];
    const float* gb7  = (const float*)d_in[18];
    const float* gcnw = (const float*)d_in[19];
    const float* gcnb = (const float*)d_in[20];
    float* out = (float*)d_out;
    __half* Th = (__half*)d_out;

    const size_t WNC = (size_t)Wn * Nn * Cn;
    const int mm_grid = (Nn + 63) / 64;    // 313 — tail block guarded

    float2* pairs = (float2*)d_ws;
    int*    offs  = (int*)((float*)d_ws + 7680000);
    int*    curs  = offs + 240384;
    int*    deg   = curs + 240000;
    __half* wT    = (__half*)deg;          // reused after scan_kernel
    float*  H     = (float*)(deg + 240000);

    // --- sort preamble ---
    hipMemsetAsync(deg, 0, (size_t)Wn * Nn * sizeof(int), stream);
    hist_kernel<<<dim3(En / 256, Wn), 256, 0, stream>>>(ei, deg);
    scan_kernel<<<Wn, 1024, 0, stream>>>(deg, offs, curs);        // last read of deg
    sortpairs_kernel<<<3000, 256, 0, stream>>>(ei, ew, curs, pairs);

    // --- weight fragment pack (fp16) into the dead deg region ---
    wprep_kernel<<<128, 256, 0, stream>>>(sw1, gw1, sw3, gw3, sw5, gw5, sw7, gw7, wT);

    // --- feature path (MFMA) ---
    inception_mfma_kernel<<<Nn / 16, 256, 0, stream>>>(
        x, sb1, gb1, sb3, gb3, sb5, gb5, sb7, gb7, wT, H);

    // hop 0
    matmul_half_kernel<<<dim3(mm_grid, Wn), 256, 0, stream>>>(H, gcnw, Th);
    agg_kernel<false><<<60000, 256, 0, stream>>>(
        Th, pairs, offs, gcnb, nullptr, H);

    // hop 1
    matmul_half_kernel<<<dim3(mm_grid, Wn), 256, 0, stream>>>(
        H, gcnw + (size_t)Wn * Cn * Cn, Th);
    agg_kernel<true><<<60000, 256, 0, stream>>>(
        Th, pairs, offs, gcnb + (size_t)Wn * Cn, x, H);
    hipMemcpyAsync(out, H, WNC * sizeof(float), hipMemcpyDeviceToDevice, stream);
}

// Round 4
// 887.938 us; speedup vs baseline: 1.2534x; 1.2534x over previous
//
#include <hip/hip_runtime.h>
#include <hip/hip_fp16.h>
#include <cstddef>

#define Wn 12
#define Nn 20000
#define Cn 64
#define En 320000
#define OFFS_STRIDE 20032
#define NBKT 79
#define BCAP 4672

typedef _Float16 h4v __attribute__((ext_vector_type(4)));
typedef _Float16 h8v __attribute__((ext_vector_type(8)));
typedef float    f4v __attribute__((ext_vector_type(4)));

__device__ __forceinline__ float elu_f(float v) {
    return v > 0.f ? v : (expf(v) - 1.f);
}

// ---------------------------------------------------------------------------
// Weight prep: pack all 4 kernel sizes (sig+gate) into MFMA B-fragment order.
// ---------------------------------------------------------------------------
__global__ __launch_bounds__(256) void wprep_kernel(
    const float* __restrict__ sw1, const float* __restrict__ gw1,
    const float* __restrict__ sw3, const float* __restrict__ gw3,
    const float* __restrict__ sw5, const float* __restrict__ gw5,
    const float* __restrict__ sw7, const float* __restrict__ gw7,
    __half* __restrict__ dst)
{
    const int i = blockIdx.x * 256 + threadIdx.x;   // 32768 total
    if (i >= 32768) return;
    const int j    = i & 7;
    const int lane = (i >> 3) & 63;
    const int slot = i >> 9;                        // 0..63
    int g, loc;
    if (slot < 4)       { g = 0; loc = slot; }
    else if (slot < 16) { g = 1; loc = slot - 4; }
    else if (slot < 36) { g = 2; loc = slot - 16; }
    else                { g = 3; loc = slot - 36; }
    const int k   = 2 * g + 1;
    const int nks = 2 * k;                          // k-steps per path
    const int sg  = (loc >= nks) ? 1 : 0;          // 0 = sig, 1 = gate
    const int s   = loc - sg * nks;
    const int t   = s >> 1;                         // tap 0..k-1
    const int ih  = s & 1;                          // ic half
    const int oc  = lane & 15;
    const int ic  = ih * 32 + (lane >> 4) * 8 + j;
    const float* src;
    switch (g * 2 + sg) {
      case 0: src = sw1; break; case 1: src = gw1; break;
      case 2: src = sw3; break; case 3: src = gw3; break;
      case 4: src = sw5; break; case 5: src = gw5; break;
      case 6: src = sw7; break; default: src = gw7; break;
    }
    dst[i] = __float2half(src[(oc * 64 + ic) * k + t]);
}

// ---------------------------------------------------------------------------
// One oc-group of the inception conv via MFMA.
// ---------------------------------------------------------------------------
template<int G>
__device__ __forceinline__ void mfma_group(
    const __half* __restrict__ wTg,    // global fragment-packed weights, group G
    __half* __restrict__ wsh,
    const __half* __restrict__ xsh,
    const float* __restrict__ sb, const float* __restrict__ gb,
    float* __restrict__ h, int nb, int tid)
{
    constexpr int NKS = 2 * (2 * G + 1);
    {
        const uint4* src = (const uint4*)wTg;
        uint4* dst = (uint4*)wsh;
        #pragma unroll
        for (int i = 0; i < 2 * G + 1; ++i)
            dst[tid + i * 256] = src[tid + i * 256];
    }
    __syncthreads();

    const int lane = tid & 63;
    const int wv   = tid >> 6;                 // 0..3
    const int node16 = lane & 15;
    const int abase = node16 * 128;
    const int swz   = (lane & 7) << 4;
    const int aoff0 = abase + ((0  + (lane >> 4) * 16) ^ swz);
    const int aoff1 = abase + ((64 + (lane >> 4) * 16) ^ swz);

    f4v accS[3], accG[3];
    #pragma unroll
    for (int m = 0; m < 3; ++m) {
        accS[m] = (f4v){0.f, 0.f, 0.f, 0.f};
        accG[m] = (f4v){0.f, 0.f, 0.f, 0.f};
    }

    #pragma unroll
    for (int s2 = 0; s2 < 2 * G + 1; ++s2) {   // dw = s2 - G
        const int dw = s2 - G;
        #pragma unroll
        for (int ih = 0; ih < 2; ++ih) {
            const int s = s2 * 2 + ih;
            const h8v bs = *(const h8v*)&wsh[(s * 64 + lane) * 8];
            const h8v bg = *(const h8v*)&wsh[((NKS + s) * 64 + lane) * 8];
            const int laneoff = ih ? aoff1 : aoff0;
            #pragma unroll
            for (int m = 0; m < 3; ++m) {
                const int w  = wv * 3 + m;
                const int wp = w + dw;
                if (wp >= 0 && wp < Wn) {      // wave-uniform
                    const h8v a = *(const h8v*)((const char*)xsh + wp * 2048 + laneoff);
                    accS[m] = __builtin_amdgcn_mfma_f32_16x16x32_f16(a, bs, accS[m], 0, 0, 0);
                    accG[m] = __builtin_amdgcn_mfma_f32_16x16x32_f16(a, bg, accG[m], 0, 0, 0);
                }
            }
        }
    }

    const float sbv = sb[node16];
    const float gbv = gb[node16];
    const int oc = G * 16 + node16;
    #pragma unroll
    for (int m = 0; m < 3; ++m) {
        const int w = wv * 3 + m;
        #pragma unroll
        for (int r = 0; r < 4; ++r) {
            const int node = (lane >> 4) * 4 + r;
            const float sv = accS[m][r] + sbv;
            const float gv = accG[m][r] + gbv;
            const float rv = sv > 0.f ? sv : 0.f;
            const float sg = 1.f / (1.f + expf(-gv));
            h[((size_t)w * Nn + nb + node) * Cn + oc] = rv * sg;
        }
    }
    __syncthreads();   // wsh reused by next group
}

// ---------------------------------------------------------------------------
// Inception gated temporal conv, MFMA version.
// ---------------------------------------------------------------------------
__global__ __launch_bounds__(256, 3) void inception_mfma_kernel(
    const float* __restrict__ x,
    const float* __restrict__ sb1, const float* __restrict__ gb1,
    const float* __restrict__ sb3, const float* __restrict__ gb3,
    const float* __restrict__ sb5, const float* __restrict__ gb5,
    const float* __restrict__ sb7, const float* __restrict__ gb7,
    const __half* __restrict__ wT,
    float* __restrict__ h)
{
    __shared__ __align__(16) __half xsh[12 * 16 * 64];   // 24,576 B
    __shared__ __align__(16) __half wsh[14336];           // 28,672 B (max group)
    const int tid = threadIdx.x;
    const int nb  = blockIdx.x * 16;

    const float4* xg = (const float4*)x;
    for (int i = tid; i < 3072; i += 256) {
        const int w = i >> 8, r = i & 255, node = r >> 4, c4 = r & 15;
        const float4 v = xg[((size_t)w * Nn + nb + node) * 16 + c4];
        h4v p = { (_Float16)v.x, (_Float16)v.y, (_Float16)v.z, (_Float16)v.w };
        const int off = w * 2048 + node * 128 + (((c4 << 3)) ^ ((node & 7) << 4));
        *(h4v*)((char*)xsh + off) = p;
    }
    mfma_group<0>(wT,         wsh, xsh, sb1, gb1, h, nb, tid);
    mfma_group<1>(wT + 2048,  wsh, xsh, sb3, gb3, h, nb, tid);
    mfma_group<2>(wT + 8192,  wsh, xsh, sb5, gb5, h, nb, tid);
    mfma_group<3>(wT + 18432, wsh, xsh, sb7, gb7, h, nb, tid);
}

// ---------------------------------------------------------------------------
// Per-window (N x 64) @ (64 x 64) matmul, fp32 in -> fp16 out. Tail guarded.
// ---------------------------------------------------------------------------
__global__ __launch_bounds__(256) void matmul_half_kernel(
    const float* __restrict__ h, const float* __restrict__ gw,
    __half* __restrict__ t)
{
    const int w  = blockIdx.y;
    const int nb = blockIdx.x * 64;
    __shared__ float wm[64 * 64];
    __shared__ float hT[64 * 64];
    const int tid = threadIdx.x;

    const float4* wsrc = (const float4*)(gw + (size_t)w * 4096);
    float4* wm4 = (float4*)wm;
    for (int i = tid; i < 1024; i += 256) wm4[i] = wsrc[i];

    {
        const int n = tid >> 2, icq = tid & 3;
        const int nclamp = (nb + n < Nn) ? (nb + n) : (Nn - 1);
        const float4* hsrc = (const float4*)(h + ((size_t)w * Nn + nclamp) * 64);
        #pragma unroll
        for (int k = 0; k < 4; ++k) {
            float4 v = hsrc[icq + 4 * k];
            int ic = (icq + 4 * k) * 4;
            hT[(ic + 0) * 64 + n] = v.x;
            hT[(ic + 1) * 64 + n] = v.y;
            hT[(ic + 2) * 64 + n] = v.z;
            hT[(ic + 3) * 64 + n] = v.w;
        }
    }
    __syncthreads();

    const int oc0 = (tid & 15) * 4;
    const int n0  = (tid >> 4) * 4;
    float acc[4][4] = {{0.f}};
    #pragma unroll
    for (int ic = 0; ic < 64; ++ic) {
        const float4 hv = *(const float4*)&hT[ic * 64 + n0];
        const float4 wv = *(const float4*)&wm[ic * 64 + oc0];
        acc[0][0] = fmaf(hv.x, wv.x, acc[0][0]);
        acc[0][1] = fmaf(hv.x, wv.y, acc[0][1]);
        acc[0][2] = fmaf(hv.x, wv.z, acc[0][2]);
        acc[0][3] = fmaf(hv.x, wv.w, acc[0][3]);
        acc[1][0] = fmaf(hv.y, wv.x, acc[1][0]);
        acc[1][1] = fmaf(hv.y, wv.y, acc[1][1]);
        acc[1][2] = fmaf(hv.y, wv.z, acc[1][2]);
        acc[1][3] = fmaf(hv.y, wv.w, acc[1][3]);
        acc[2][0] = fmaf(hv.z, wv.x, acc[2][0]);
        acc[2][1] = fmaf(hv.z, wv.y, acc[2][1]);
        acc[2][2] = fmaf(hv.z, wv.z, acc[2][2]);
        acc[2][3] = fmaf(hv.z, wv.w, acc[2][3]);
        acc[3][0] = fmaf(hv.w, wv.x, acc[3][0]);
        acc[3][1] = fmaf(hv.w, wv.y, acc[3][1]);
        acc[3][2] = fmaf(hv.w, wv.z, acc[3][2]);
        acc[3][3] = fmaf(hv.w, wv.w, acc[3][3]);
    }

    #pragma unroll
    for (int i = 0; i < 4; ++i) {
        if (nb + n0 + i < Nn) {
            __half2 lo = __floats2half2_rn(acc[i][0], acc[i][1]);
            __half2 hi = __floats2half2_rn(acc[i][2], acc[i][3]);
            uint2 pack;
            pack.x = *(const unsigned int*)&lo;
            pack.y = *(const unsigned int*)&hi;
            *(uint2*)&t[((size_t)w * Nn + nb + n0 + i) * 64 + oc0] = pack;
        }
    }
}

// ---------------------------------------------------------------------------
// Counting-sort preamble: histogram of dst per window.
// ---------------------------------------------------------------------------
__global__ __launch_bounds__(256) void hist_kernel(
    const int* __restrict__ ei, int* __restrict__ deg)
{
    const int w = blockIdx.y;
    const int e = blockIdx.x * 256 + threadIdx.x;
    const int dst = ei[(size_t)w * 2 * En + En + e];
    atomicAdd(&deg[w * Nn + dst], 1);
}

// 12 blocks x 1024 threads: hierarchical scan. (curs no longer needed.)
__global__ __launch_bounds__(1024) void scan_kernel(
    const int* __restrict__ deg, int* __restrict__ offs)
{
    const int w   = blockIdx.x;
    const int tid = threadIdx.x;
    const int lane = tid & 63;
    const int wv   = tid >> 6;            // 0..15
    __shared__ int wsum[16];
    __shared__ int ctot;
    int running = 0;
    for (int base = 0; base < Nn; base += 1024) {
        const int i = base + tid;
        int v = (i < Nn) ? deg[w * Nn + i] : 0;
        int sum = v;
        #pragma unroll
        for (int d = 1; d < 64; d <<= 1) {
            int t = __shfl_up(sum, d);
            if (lane >= d) sum += t;
        }
        if (lane == 63) wsum[wv] = sum;
        __syncthreads();
        if (tid < 16) {
            int orig = wsum[tid];
            int s = orig;
            #pragma unroll
            for (int d = 1; d < 16; d <<= 1) {
                int t = __shfl_up(s, d);
                if (tid >= d) s += t;
            }
            wsum[tid] = s - orig;         // exclusive across waves
            if (tid == 15) ctot = s;
        }
        __syncthreads();
        if (i < Nn) {
            offs[w * OFFS_STRIDE + i] = running + wsum[wv] + (sum - v);
        }
        running += ctot;
        __syncthreads();
    }
    if (tid == 0) offs[w * OFFS_STRIDE + Nn] = running;
}

// ---------------------------------------------------------------------------
// Bucketed sort, phase A: bin 2560 edges/block into 79 coarse dst-buckets
// (dst>>8). Edges are compacted bucket-contiguous in LDS, segments reserved
// with ONE global atomic per bucket, then flushed with consecutive-address
// runs (~260 B per bucket per block) -> line-granular HBM writes instead of
// the 8 B scattered stores that cost 64 B each (round-1/3 counters: 227-241
// MB WRITE_SIZE for a 31 MB logical scatter). Entry pack: src (16b) |
// dst&255 (bits 16..23), weight bits in .y.
// ---------------------------------------------------------------------------
__global__ __launch_bounds__(256) void bucketA_kernel(
    const int* __restrict__ ei, const float* __restrict__ ew,
    int* __restrict__ bcur, uint2* __restrict__ bstr)
{
    const int w   = blockIdx.y;
    const int tid = threadIdx.x;
    __shared__ uint2 compact[2560];
    __shared__ unsigned char bkid[2560];
    __shared__ int rcnt[NBKT], rbase[NBKT], sbase[NBKT];
    __shared__ int sc[128];

    const int* eis = ei + (size_t)w * 2 * En;
    const float* ews = ew + (size_t)w * En;
    const int e0 = blockIdx.x * 2560;

    if (tid < NBKT) rcnt[tid] = 0;
    __syncthreads();

    int myb[10], myr[10];
    uint2 mye[10];
    #pragma unroll
    for (int it = 0; it < 10; ++it) {
        const int e = e0 + it * 256 + tid;
        const int s = eis[e];
        const int d = eis[En + e];
        const float wt = ews[e];
        const int bk = d >> 8;
        myb[it] = bk;
        mye[it].x = (unsigned)s | ((unsigned)(d & 255) << 16);
        mye[it].y = __float_as_uint(wt);
        myr[it] = atomicAdd(&rcnt[bk], 1);
    }
    __syncthreads();
    if (tid < 128) sc[tid] = (tid < NBKT) ? rcnt[tid] : 0;
    __syncthreads();
    #pragma unroll
    for (int dlt = 1; dlt < 128; dlt <<= 1) {
        int t = (tid < 128 && tid >= dlt) ? sc[tid - dlt] : 0;
        __syncthreads();
        if (tid < 128) sc[tid] += t;
        __syncthreads();
    }
    if (tid < NBKT) {
        rbase[tid] = sc[tid] - rcnt[tid];                       // excl within block
        sbase[tid] = atomicAdd(&bcur[w * 80 + tid], rcnt[tid]); // segment in stream
    }
    __syncthreads();
    #pragma unroll
    for (int it = 0; it < 10; ++it) {
        const int p = rbase[myb[it]] + myr[it];
        compact[p] = mye[it];
        bkid[p] = (unsigned char)myb[it];
    }
    __syncthreads();
    for (int i = tid; i < 2560; i += 256) {
        const int bk = bkid[i];
        int off = sbase[bk] + (i - rbase[bk]);
        if (off >= BCAP) off = BCAP - 1;   // ~9 sigma guard, never expected
        bstr[((size_t)w * NBKT + bk) * BCAP + off] = compact[i];
    }
}

// ---------------------------------------------------------------------------
// Bucketed sort, phase B: one block per (bucket, window). Load the bucket
// stream (~4096 edges) into registers, counting-sort by exact dst in LDS
// (local hist == global per-dst counts since a dst lives in exactly one
// bucket), then write the bucket's fully-sorted contiguous segment to pairs
// with perfectly coalesced full-line stores at offs[bk*256].
// ---------------------------------------------------------------------------
__global__ __launch_bounds__(256) void bucketB_kernel(
    const uint2* __restrict__ bstr, const int* __restrict__ bcur,
    const int* __restrict__ offs, float2* __restrict__ pairs)
{
    const int bk = blockIdx.x, w = blockIdx.y;
    const int tid = threadIdx.x;
    __shared__ uint2 sorted[BCAP];
    __shared__ int lhist[256], lbase[256], wsum[4];
    int n = bcur[w * 80 + bk];
    if (n > BCAP) n = BCAP;
    const uint2* src = bstr + ((size_t)w * NBKT + bk) * BCAP;

    lhist[tid] = 0;
    __syncthreads();

    constexpr int MAXE = (BCAP + 255) / 256;   // 19
    uint2 mye[MAXE];
    short myd[MAXE], myr[MAXE];
    #pragma unroll
    for (int it = 0; it < MAXE; ++it) {
        const int i = tid + it * 256;
        if (i < n) {
            const uint2 e = src[i];
            mye[it] = e;
            const int dl = (e.x >> 16) & 255;
            myd[it] = (short)dl;
            myr[it] = (short)atomicAdd(&lhist[dl], 1);
        }
    }
    __syncthreads();
    {
        const int lane = tid & 63, wv = tid >> 6;
        const int v = lhist[tid];
        int sum = v;
        #pragma unroll
        for (int dlt = 1; dlt < 64; dlt <<= 1) {
            int t = __shfl_up(sum, dlt);
            if (lane >= dlt) sum += t;
        }
        if (lane == 63) wsum[wv] = sum;
        __syncthreads();
        if (tid < 4) {
            int o = wsum[tid], s2 = o;
            #pragma unroll
            for (int dlt = 1; dlt < 4; dlt <<= 1) {
                int t = __shfl_up(s2, dlt);
                if (tid >= dlt) s2 += t;
            }
            wsum[tid] = s2 - o;            // exclusive across waves
        }
        __syncthreads();
        lbase[tid] = wsum[wv] + sum - v;   // exclusive per-dst base
    }
    __syncthreads();
    #pragma unroll
    for (int it = 0; it < MAXE; ++it) {
        const int i = tid + it * 256;
        if (i < n)
            sorted[lbase[myd[it]] + myr[it]] = mye[it];
    }
    __syncthreads();
    const int gbase = offs[w * OFFS_STRIDE + bk * 256];
    float2* pw = pairs + (size_t)w * En + gbase;
    for (int i = tid; i < n; i += 256) {
        const uint2 e = sorted[i];
        pw[i] = make_float2(__int_as_float((int)(e.x & 0xFFFFu)), __uint_as_float(e.y));
    }
}

// ---------------------------------------------------------------------------
// Aggregation: one wave per dst; 2 edges in flight (32 lanes x __half2 each,
// 128 B/edge in half the instructions). XCD-affinity swizzle: blocks of
// window w land on b%8=f(w) -> each XCD's L2 holds <=2 t-slabs (5 MB) instead
// of all 12 (31 MB thrash). (round-1 form; NT variants regressed in round 3.)
// ---------------------------------------------------------------------------
template<bool LAST>
__global__ __launch_bounds__(256) void agg_kernel(
    const __half* __restrict__ t, const float2* __restrict__ pairs,
    const int* __restrict__ offs, const float* __restrict__ b,
    const float* __restrict__ x, float* __restrict__ out)
{
    const int blk = blockIdx.x;
    const int r = blk & 7, q = blk >> 3;
    int w, ng;
    if (q < 5000) { w = r; ng = q; }
    else { int q2 = q - 5000; w = 8 + (r >> 1); ng = q2 * 2 + (r & 1); }

    const int d    = ng * 4 + (threadIdx.x >> 6);
    const int lane = threadIdx.x & 63;
    const int hgrp = lane >> 5;           // which of 2 concurrent edges
    const int c    = lane & 31;           // channel pair index
    const int* ow  = offs + w * OFFS_STRIDE;
    const int beg = ow[d];
    const int end = ow[d + 1];
    const float2* pw = pairs + (size_t)w * En;
    const __half* tw = t + (size_t)w * Nn * Cn;

    float ax = 0.f, ay = 0.f;
    int i = beg;
    for (; i + 4 <= end; i += 4) {
        float2 p0 = pw[i + hgrp];
        float2 p1 = pw[i + 2 + hgrp];
        float2 f0 = __half22float2(*(const __half2*)&tw[(size_t)__float_as_int(p0.x) * Cn + 2 * c]);
        float2 f1 = __half22float2(*(const __half2*)&tw[(size_t)__float_as_int(p1.x) * Cn + 2 * c]);
        ax = fmaf(p0.y, f0.x, ax);
        ay = fmaf(p0.y, f0.y, ay);
        ax = fmaf(p1.y, f1.x, ax);
        ay = fmaf(p1.y, f1.y, ay);
    }
    if (i + 2 <= end) {
        float2 p0 = pw[i + hgrp];
        float2 f0 = __half22float2(*(const __half2*)&tw[(size_t)__float_as_int(p0.x) * Cn + 2 * c]);
        ax = fmaf(p0.y, f0.x, ax);
        ay = fmaf(p0.y, f0.y, ay);
        i += 2;
    }
    if (i < end && hgrp == 0) {
        float2 p0 = pw[i];
        float2 f0 = __half22float2(*(const __half2*)&tw[(size_t)__float_as_int(p0.x) * Cn + 2 * c]);
        ax = fmaf(p0.y, f0.x, ax);
        ay = fmaf(p0.y, f0.y, ay);
    }

    ax += __shfl_xor(ax, 32);
    ay += __shfl_xor(ay, 32);

    if (hgrp == 0) {
        const float2 bv = *(const float2*)&b[w * Cn + 2 * c];
        float vx = elu_f(ax + bv.x);
        float vy = elu_f(ay + bv.y);
        const size_t oi = ((size_t)w * Nn + d) * Cn + 2 * c;
        if (LAST) {
            const float2 xv = *(const float2*)&x[oi];
            vx += xv.x;
            vy += xv.y;
        }
        *(float2*)&out[oi] = make_float2(vx, vy);
    }
}

// ---------------------------------------------------------------------------
// ws layout (floats):
//   [0)          pairs : 7,680,000
//   [7,680,000)  offs  :   240,384 (int)
//   [7,920,384)  bcur  :   240,000 (int)  -- was curs; only 12*80 used
//   [8,160,384)  deg   :   240,000 (int)  -- reused as wT (32768 halfs) after scan
//   [8,400,384)  H     : 15,360,000      -- doubles as bstr (35.4 MB) before
//                                           inception overwrites it (in-order)
// t (fp16) lives in d_out between matmul and agg; final result built in H,
// then copied to d_out.
// ---------------------------------------------------------------------------
extern "C" void kernel_launch(void* const* d_in, const int* in_sizes, int n_in,
                              void* d_out, int out_size, void* d_ws, size_t ws_size,
                              hipStream_t stream)
{
    const float* x    = (const float*)d_in[0];
    const int*   ei   = (const int*)d_in[1];
    const float* ew   = (const float*)d_in[2];
    const float* sw1  = (const float*)d_in[3];
    const float* sb1  = (const float*)d_in[4];
    const float* gw1  = (const float*)d_in[5];
    const float* gb1  = (const float*)d_in[6];
    const float* sw3  = (const float*)d_in[7];
    const float* sb3  = (const float*)d_in[8];
    const float* gw3  = (const float*)d_in[9];
    const float* gb3  = (const float*)d_in[10];
    const float* sw5  = (const float*)d_in[11];
    const float* sb5  = (const float*)d_in[12];
    const float* gw5  = (const float*)d_in[13];
    const float* gb5  = (const float*)d_in[14];
    const float* sw7  = (const float*)d_in[15];
    const float* sb7  = (const float*)d_in[16];
    const float* gw7  = (const float*)d_in[17];
    const float* gb7  = (const float*)d_in[18];
    const float* gcnw = (const float*)d_in[19];
    const float* gcnb = (const float*)d_in[20];
    float* out = (float*)d_out;
    __half* Th = (__half*)d_out;

    const size_t WNC = (size_t)Wn * Nn * Cn;
    const int mm_grid = (Nn + 63) / 64;    // 313 — tail block guarded

    float2* pairs = (float2*)d_ws;
    int*    offs  = (int*)((float*)d_ws + 7680000);
    int*    bcur  = offs + 240384;
    int*    deg   = bcur + 240000;
    __half* wT    = (__half*)deg;          // reused after scan_kernel
    float*  H     = (float*)(deg + 240000);
    uint2*  bstr  = (uint2*)H;             // phase-A bucket streams (dead after B)

    // --- sort preamble ---
    hipMemsetAsync(deg, 0, (size_t)Wn * Nn * sizeof(int), stream);
    hipMemsetAsync(bcur, 0, (size_t)Wn * 80 * sizeof(int), stream);
    hist_kernel<<<dim3(En / 256, Wn), 256, 0, stream>>>(ei, deg);
    scan_kernel<<<Wn, 1024, 0, stream>>>(deg, offs);   // last read of deg
    bucketA_kernel<<<dim3(En / 2560, Wn), 256, 0, stream>>>(ei, ew, bcur, bstr);
    bucketB_kernel<<<dim3(NBKT, Wn), 256, 0, stream>>>(bstr, bcur, offs, pairs);

    // --- weight fragment pack (fp16) into the dead deg region ---
    wprep_kernel<<<128, 256, 0, stream>>>(sw1, gw1, sw3, gw3, sw5, gw5, sw7, gw7, wT);

    // --- feature path (MFMA) ---
    inception_mfma_kernel<<<Nn / 16, 256, 0, stream>>>(
        x, sb1, gb1, sb3, gb3, sb5, gb5, sb7, gb7, wT, H);

    // hop 0
    matmul_half_kernel<<<dim3(mm_grid, Wn), 256, 0, stream>>>(H, gcnw, Th);
    agg_kernel<false><<<60000, 256, 0, stream>>>(
        Th, pairs, offs, gcnb, nullptr, H);

    // hop 1
    matmul_half_kernel<<<dim3(mm_grid, Wn), 256, 0, stream>>>(
        H, gcnw + (size_t)Wn * Cn * Cn, Th);
    agg_kernel<true><<<60000, 256, 0, stream>>>(
        Th, pairs, offs, gcnb + (size_t)Wn * Cn, x, H);
    hipMemcpyAsync(out, H, WNC * sizeof(float), hipMemcpyDeviceToDevice, stream);
}

// Round 6
// 712.830 us; speedup vs baseline: 1.5612x; 1.2457x over previous
//
#include <hip/hip_runtime.h>
#include <hip/hip_fp16.h>
#include <cstddef>

#define Wn 12
#define Nn 20000
#define Cn 64
#define En 320000
#define OFFS_STRIDE 20032
#define NBKT 79
#define BCAP 4672

typedef _Float16 h4v __attribute__((ext_vector_type(4)));
typedef _Float16 h8v __attribute__((ext_vector_type(8)));
typedef float    f4v __attribute__((ext_vector_type(4)));

__device__ __forceinline__ float elu_f(float v) {
    return v > 0.f ? v : (expf(v) - 1.f);
}

// ---------------------------------------------------------------------------
// Weight prep: pack all 4 kernel sizes (sig+gate) into MFMA B-fragment order.
// ---------------------------------------------------------------------------
__global__ __launch_bounds__(256) void wprep_kernel(
    const float* __restrict__ sw1, const float* __restrict__ gw1,
    const float* __restrict__ sw3, const float* __restrict__ gw3,
    const float* __restrict__ sw5, const float* __restrict__ gw5,
    const float* __restrict__ sw7, const float* __restrict__ gw7,
    __half* __restrict__ dst)
{
    const int i = blockIdx.x * 256 + threadIdx.x;   // 32768 total
    if (i >= 32768) return;
    const int j    = i & 7;
    const int lane = (i >> 3) & 63;
    const int slot = i >> 9;                        // 0..63
    int g, loc;
    if (slot < 4)       { g = 0; loc = slot; }
    else if (slot < 16) { g = 1; loc = slot - 4; }
    else if (slot < 36) { g = 2; loc = slot - 16; }
    else                { g = 3; loc = slot - 36; }
    const int k   = 2 * g + 1;
    const int nks = 2 * k;                          // k-steps per path
    const int sg  = (loc >= nks) ? 1 : 0;          // 0 = sig, 1 = gate
    const int s   = loc - sg * nks;
    const int t   = s >> 1;                         // tap 0..k-1
    const int ih  = s & 1;                          // ic half
    const int oc  = lane & 15;
    const int ic  = ih * 32 + (lane >> 4) * 8 + j;
    const float* src;
    switch (g * 2 + sg) {
      case 0: src = sw1; break; case 1: src = gw1; break;
      case 2: src = sw3; break; case 3: src = gw3; break;
      case 4: src = sw5; break; case 5: src = gw5; break;
      case 6: src = sw7; break; default: src = gw7; break;
    }
    dst[i] = __float2half(src[(oc * 64 + ic) * k + t]);
}

// ---------------------------------------------------------------------------
// One oc-group of the inception conv via MFMA.
// ---------------------------------------------------------------------------
template<int G>
__device__ __forceinline__ void mfma_group(
    const __half* __restrict__ wTg,    // global fragment-packed weights, group G
    __half* __restrict__ wsh,
    const __half* __restrict__ xsh,
    const float* __restrict__ sb, const float* __restrict__ gb,
    float* __restrict__ h, int nb, int tid)
{
    constexpr int NKS = 2 * (2 * G + 1);
    {
        const uint4* src = (const uint4*)wTg;
        uint4* dst = (uint4*)wsh;
        #pragma unroll
        for (int i = 0; i < 2 * G + 1; ++i)
            dst[tid + i * 256] = src[tid + i * 256];
    }
    __syncthreads();

    const int lane = tid & 63;
    const int wv   = tid >> 6;                 // 0..3
    const int node16 = lane & 15;
    const int abase = node16 * 128;
    const int swz   = (lane & 7) << 4;
    const int aoff0 = abase + ((0  + (lane >> 4) * 16) ^ swz);
    const int aoff1 = abase + ((64 + (lane >> 4) * 16) ^ swz);

    f4v accS[3], accG[3];
    #pragma unroll
    for (int m = 0; m < 3; ++m) {
        accS[m] = (f4v){0.f, 0.f, 0.f, 0.f};
        accG[m] = (f4v){0.f, 0.f, 0.f, 0.f};
    }

    #pragma unroll
    for (int s2 = 0; s2 < 2 * G + 1; ++s2) {   // dw = s2 - G
        const int dw = s2 - G;
        #pragma unroll
        for (int ih = 0; ih < 2; ++ih) {
            const int s = s2 * 2 + ih;
            const h8v bs = *(const h8v*)&wsh[(s * 64 + lane) * 8];
            const h8v bg = *(const h8v*)&wsh[((NKS + s) * 64 + lane) * 8];
            const int laneoff = ih ? aoff1 : aoff0;
            #pragma unroll
            for (int m = 0; m < 3; ++m) {
                const int w  = wv * 3 + m;
                const int wp = w + dw;
                if (wp >= 0 && wp < Wn) {      // wave-uniform
                    const h8v a = *(const h8v*)((const char*)xsh + wp * 2048 + laneoff);
                    accS[m] = __builtin_amdgcn_mfma_f32_16x16x32_f16(a, bs, accS[m], 0, 0, 0);
                    accG[m] = __builtin_amdgcn_mfma_f32_16x16x32_f16(a, bg, accG[m], 0, 0, 0);
                }
            }
        }
    }

    const float sbv = sb[node16];
    const float gbv = gb[node16];
    const int oc = G * 16 + node16;
    #pragma unroll
    for (int m = 0; m < 3; ++m) {
        const int w = wv * 3 + m;
        #pragma unroll
        for (int r = 0; r < 4; ++r) {
            const int node = (lane >> 4) * 4 + r;
            const float sv = accS[m][r] + sbv;
            const float gv = accG[m][r] + gbv;
            const float rv = sv > 0.f ? sv : 0.f;
            const float sg = 1.f / (1.f + expf(-gv));
            h[((size_t)w * Nn + nb + node) * Cn + oc] = rv * sg;
        }
    }
    __syncthreads();   // wsh reused by next group
}

// ---------------------------------------------------------------------------
// Inception gated temporal conv, MFMA version.
// ---------------------------------------------------------------------------
__global__ __launch_bounds__(256, 3) void inception_mfma_kernel(
    const float* __restrict__ x,
    const float* __restrict__ sb1, const float* __restrict__ gb1,
    const float* __restrict__ sb3, const float* __restrict__ gb3,
    const float* __restrict__ sb5, const float* __restrict__ gb5,
    const float* __restrict__ sb7, const float* __restrict__ gb7,
    const __half* __restrict__ wT,
    float* __restrict__ h)
{
    __shared__ __align__(16) __half xsh[12 * 16 * 64];   // 24,576 B
    __shared__ __align__(16) __half wsh[14336];           // 28,672 B (max group)
    const int tid = threadIdx.x;
    const int nb  = blockIdx.x * 16;

    const float4* xg = (const float4*)x;
    for (int i = tid; i < 3072; i += 256) {
        const int w = i >> 8, r = i & 255, node = r >> 4, c4 = r & 15;
        const float4 v = xg[((size_t)w * Nn + nb + node) * 16 + c4];
        h4v p = { (_Float16)v.x, (_Float16)v.y, (_Float16)v.z, (_Float16)v.w };
        const int off = w * 2048 + node * 128 + (((c4 << 3)) ^ ((node & 7) << 4));
        *(h4v*)((char*)xsh + off) = p;
    }
    mfma_group<0>(wT,         wsh, xsh, sb1, gb1, h, nb, tid);
    mfma_group<1>(wT + 2048,  wsh, xsh, sb3, gb3, h, nb, tid);
    mfma_group<2>(wT + 8192,  wsh, xsh, sb5, gb5, h, nb, tid);
    mfma_group<3>(wT + 18432, wsh, xsh, sb7, gb7, h, nb, tid);
}

// ---------------------------------------------------------------------------
// Per-window (N x 64) @ (64 x 64) matmul, fp32 in -> fp16 out. Tail guarded.
// ---------------------------------------------------------------------------
__global__ __launch_bounds__(256) void matmul_half_kernel(
    const float* __restrict__ h, const float* __restrict__ gw,
    __half* __restrict__ t)
{
    const int w  = blockIdx.y;
    const int nb = blockIdx.x * 64;
    __shared__ float wm[64 * 64];
    __shared__ float hT[64 * 64];
    const int tid = threadIdx.x;

    const float4* wsrc = (const float4*)(gw + (size_t)w * 4096);
    float4* wm4 = (float4*)wm;
    for (int i = tid; i < 1024; i += 256) wm4[i] = wsrc[i];

    {
        const int n = tid >> 2, icq = tid & 3;
        const int nclamp = (nb + n < Nn) ? (nb + n) : (Nn - 1);
        const float4* hsrc = (const float4*)(h + ((size_t)w * Nn + nclamp) * 64);
        #pragma unroll
        for (int k = 0; k < 4; ++k) {
            float4 v = hsrc[icq + 4 * k];
            int ic = (icq + 4 * k) * 4;
            hT[(ic + 0) * 64 + n] = v.x;
            hT[(ic + 1) * 64 + n] = v.y;
            hT[(ic + 2) * 64 + n] = v.z;
            hT[(ic + 3) * 64 + n] = v.w;
        }
    }
    __syncthreads();

    const int oc0 = (tid & 15) * 4;
    const int n0  = (tid >> 4) * 4;
    float acc[4][4] = {{0.f}};
    #pragma unroll
    for (int ic = 0; ic < 64; ++ic) {
        const float4 hv = *(const float4*)&hT[ic * 64 + n0];
        const float4 wv = *(const float4*)&wm[ic * 64 + oc0];
        acc[0][0] = fmaf(hv.x, wv.x, acc[0][0]);
        acc[0][1] = fmaf(hv.x, wv.y, acc[0][1]);
        acc[0][2] = fmaf(hv.x, wv.z, acc[0][2]);
        acc[0][3] = fmaf(hv.x, wv.w, acc[0][3]);
        acc[1][0] = fmaf(hv.y, wv.x, acc[1][0]);
        acc[1][1] = fmaf(hv.y, wv.y, acc[1][1]);
        acc[1][2] = fmaf(hv.y, wv.z, acc[1][2]);
        acc[1][3] = fmaf(hv.y, wv.w, acc[1][3]);
        acc[2][0] = fmaf(hv.z, wv.x, acc[2][0]);
        acc[2][1] = fmaf(hv.z, wv.y, acc[2][1]);
        acc[2][2] = fmaf(hv.z, wv.z, acc[2][2]);
        acc[2][3] = fmaf(hv.z, wv.w, acc[2][3]);
        acc[3][0] = fmaf(hv.w, wv.x, acc[3][0]);
        acc[3][1] = fmaf(hv.w, wv.y, acc[3][1]);
        acc[3][2] = fmaf(hv.w, wv.z, acc[3][2]);
        acc[3][3] = fmaf(hv.w, wv.w, acc[3][3]);
    }

    #pragma unroll
    for (int i = 0; i < 4; ++i) {
        if (nb + n0 + i < Nn) {
            __half2 lo = __floats2half2_rn(acc[i][0], acc[i][1]);
            __half2 hi = __floats2half2_rn(acc[i][2], acc[i][3]);
            uint2 pack;
            pack.x = *(const unsigned int*)&lo;
            pack.y = *(const unsigned int*)&hi;
            *(uint2*)&t[((size_t)w * Nn + nb + n0 + i) * 64 + oc0] = pack;
        }
    }
}

// ---------------------------------------------------------------------------
// Bucketed sort, phase A: bin 2560 edges/block into 79 coarse dst-buckets
// (dst>>8). Edges are compacted bucket-contiguous in LDS, segments reserved
// with ONE global atomic per bucket, then flushed with consecutive-address
// runs -> line-granular HBM writes. Entry pack: src (16b) | dst&255
// (bits 16..23), weight bits in .y.
// ---------------------------------------------------------------------------
__global__ __launch_bounds__(256) void bucketA_kernel(
    const int* __restrict__ ei, const float* __restrict__ ew,
    int* __restrict__ bcur, uint2* __restrict__ bstr)
{
    const int w   = blockIdx.y;
    const int tid = threadIdx.x;
    __shared__ uint2 compact[2560];
    __shared__ unsigned char bkid[2560];
    __shared__ int rcnt[NBKT], rbase[NBKT], sbase[NBKT];
    __shared__ int sc[128];

    const int* eis = ei + (size_t)w * 2 * En;
    const float* ews = ew + (size_t)w * En;
    const int e0 = blockIdx.x * 2560;

    if (tid < NBKT) rcnt[tid] = 0;
    __syncthreads();

    int myb[10], myr[10];
    uint2 mye[10];
    #pragma unroll
    for (int it = 0; it < 10; ++it) {
        const int e = e0 + it * 256 + tid;
        const int s = eis[e];
        const int d = eis[En + e];
        const float wt = ews[e];
        const int bk = d >> 8;
        myb[it] = bk;
        mye[it].x = (unsigned)s | ((unsigned)(d & 255) << 16);
        mye[it].y = __float_as_uint(wt);
        myr[it] = atomicAdd(&rcnt[bk], 1);
    }
    __syncthreads();
    if (tid < 128) sc[tid] = (tid < NBKT) ? rcnt[tid] : 0;
    __syncthreads();
    #pragma unroll
    for (int dlt = 1; dlt < 128; dlt <<= 1) {
        int t = (tid < 128 && tid >= dlt) ? sc[tid - dlt] : 0;
        __syncthreads();
        if (tid < 128) sc[tid] += t;
        __syncthreads();
    }
    if (tid < NBKT) {
        rbase[tid] = sc[tid] - rcnt[tid];                       // excl within block
        sbase[tid] = atomicAdd(&bcur[w * 80 + tid], rcnt[tid]); // segment in stream
    }
    __syncthreads();
    #pragma unroll
    for (int it = 0; it < 10; ++it) {
        const int p = rbase[myb[it]] + myr[it];
        compact[p] = mye[it];
        bkid[p] = (unsigned char)myb[it];
    }
    __syncthreads();
    for (int i = tid; i < 2560; i += 256) {
        const int bk = bkid[i];
        int off = sbase[bk] + (i - rbase[bk]);
        if (off >= BCAP) off = BCAP - 1;   // ~9 sigma guard, never expected
        bstr[((size_t)w * NBKT + bk) * BCAP + off] = compact[i];
    }
}

// ---------------------------------------------------------------------------
// Tiny scan over the 12 x 79 bucket counts -> exclusive bucket bases.
// One block, 12 waves (one per window). Replaces the global hist+scan over
// 240K dst bins (whose 3.84M scattered atomics cost 118 MB of HBM writes).
// ---------------------------------------------------------------------------
__global__ __launch_bounds__(768) void bscan_kernel(
    const int* __restrict__ bcur, int* __restrict__ bbase)
{
    const int lane = threadIdx.x & 63;
    const int w    = threadIdx.x >> 6;   // 0..11
    const int c0 = (lane < NBKT) ? bcur[w * 80 + lane] : 0;
    int s = c0;
    #pragma unroll
    for (int d = 1; d < 64; d <<= 1) {
        int t = __shfl_up(s, d);
        if (lane >= d) s += t;
    }
    const int tot0 = __shfl(s, 63);
    const int c1 = (lane + 64 < NBKT) ? bcur[w * 80 + 64 + lane] : 0;
    int s1 = c1;
    #pragma unroll
    for (int d = 1; d < 64; d <<= 1) {
        int t = __shfl_up(s1, d);
        if (lane >= d) s1 += t;
    }
    s1 += tot0;
    bbase[w * 80 + lane] = s - c0;
    if (lane + 64 < NBKT) bbase[w * 80 + 64 + lane] = s1 - c1;
}

// ---------------------------------------------------------------------------
// Bucketed sort, phase B: one block per (bucket, window). Load the bucket
// stream into registers, counting-sort by exact dst in LDS (local hist ==
// global per-dst counts since a dst lives in exactly one bucket), write the
// bucket's fully-sorted contiguous segment to pairs with coalesced stores,
// AND emit the global CSR offsets: offs[w][bk*256+t] = bbase + lbase[t].
// ---------------------------------------------------------------------------
__global__ __launch_bounds__(256) void bucketB_kernel(
    const uint2* __restrict__ bstr, const int* __restrict__ bcur,
    const int* __restrict__ bbase, int* __restrict__ offs,
    float2* __restrict__ pairs)
{
    const int bk = blockIdx.x, w = blockIdx.y;
    const int tid = threadIdx.x;
    __shared__ uint2 sorted[BCAP];
    __shared__ int lhist[256], lbase[256], wsum[4];
    int n = bcur[w * 80 + bk];
    if (n > BCAP) n = BCAP;
    const int gbase = bbase[w * 80 + bk];
    const uint2* src = bstr + ((size_t)w * NBKT + bk) * BCAP;

    lhist[tid] = 0;
    __syncthreads();

    constexpr int MAXE = (BCAP + 255) / 256;   // 19
    uint2 mye[MAXE];
    short myd[MAXE], myr[MAXE];
    #pragma unroll
    for (int it = 0; it < MAXE; ++it) {
        const int i = tid + it * 256;
        if (i < n) {
            const uint2 e = src[i];
            mye[it] = e;
            const int dl = (e.x >> 16) & 255;
            myd[it] = (short)dl;
            myr[it] = (short)atomicAdd(&lhist[dl], 1);
        }
    }
    __syncthreads();
    {
        const int lane = tid & 63, wv = tid >> 6;
        const int v = lhist[tid];
        int sum = v;
        #pragma unroll
        for (int dlt = 1; dlt < 64; dlt <<= 1) {
            int t = __shfl_up(sum, dlt);
            if (lane >= dlt) sum += t;
        }
        if (lane == 63) wsum[wv] = sum;
        __syncthreads();
        if (tid < 4) {
            int o = wsum[tid], s2 = o;
            #pragma unroll
            for (int dlt = 1; dlt < 4; dlt <<= 1) {
                int t = __shfl_up(s2, dlt);
                if (tid >= dlt) s2 += t;
            }
            wsum[tid] = s2 - o;            // exclusive across waves
        }
        __syncthreads();
        const int be = wsum[wv] + sum - v; // exclusive per-dst base
        lbase[tid] = be;
        const int d = bk * 256 + tid;
        if (d < Nn) offs[w * OFFS_STRIDE + d] = gbase + be;
        if (bk == NBKT - 1 && tid == 0) offs[w * OFFS_STRIDE + Nn] = En;
    }
    __syncthreads();
    #pragma unroll
    for (int it = 0; it < MAXE; ++it) {
        const int i = tid + it * 256;
        if (i < n)
            sorted[lbase[myd[it]] + myr[it]] = mye[it];
    }
    __syncthreads();
    float2* pw = pairs + (size_t)w * En + gbase;
    for (int i = tid; i < n; i += 256) {
        const uint2 e = sorted[i];
        pw[i] = make_float2(__int_as_float((int)(e.x & 0xFFFFu)), __uint_as_float(e.y));
    }
}

// ---------------------------------------------------------------------------
// Aggregation: one wave per dst; 2 edges in flight (32 lanes x __half2 each,
// 128 B/edge in half the instructions). XCD-affinity swizzle: blocks of
// window w land on b%8=f(w) -> each XCD's L2 holds <=2 t-slabs (5 MB) instead
// of all 12 (31 MB thrash).
// ---------------------------------------------------------------------------
template<bool LAST>
__global__ __launch_bounds__(256) void agg_kernel(
    const __half* __restrict__ t, const float2* __restrict__ pairs,
    const int* __restrict__ offs, const float* __restrict__ b,
    const float* __restrict__ x, float* __restrict__ out)
{
    const int blk = blockIdx.x;
    const int r = blk & 7, q = blk >> 3;
    int w, ng;
    if (q < 5000) { w = r; ng = q; }
    else { int q2 = q - 5000; w = 8 + (r >> 1); ng = q2 * 2 + (r & 1); }

    const int d    = ng * 4 + (threadIdx.x >> 6);
    const int lane = threadIdx.x & 63;
    const int hgrp = lane >> 5;           // which of 2 concurrent edges
    const int c    = lane & 31;           // channel pair index
    const int* ow  = offs + w * OFFS_STRIDE;
    const int beg = ow[d];
    const int end = ow[d + 1];
    const float2* pw = pairs + (size_t)w * En;
    const __half* tw = t + (size_t)w * Nn * Cn;

    float ax = 0.f, ay = 0.f;
    int i = beg;
    for (; i + 4 <= end; i += 4) {
        float2 p0 = pw[i + hgrp];
        float2 p1 = pw[i + 2 + hgrp];
        float2 f0 = __half22float2(*(const __half2*)&tw[(size_t)__float_as_int(p0.x) * Cn + 2 * c]);
        float2 f1 = __half22float2(*(const __half2*)&tw[(size_t)__float_as_int(p1.x) * Cn + 2 * c]);
        ax = fmaf(p0.y, f0.x, ax);
        ay = fmaf(p0.y, f0.y, ay);
        ax = fmaf(p1.y, f1.x, ax);
        ay = fmaf(p1.y, f1.y, ay);
    }
    if (i + 2 <= end) {
        float2 p0 = pw[i + hgrp];
        float2 f0 = __half22float2(*(const __half2*)&tw[(size_t)__float_as_int(p0.x) * Cn + 2 * c]);
        ax = fmaf(p0.y, f0.x, ax);
        ay = fmaf(p0.y, f0.y, ay);
        i += 2;
    }
    if (i < end && hgrp == 0) {
        float2 p0 = pw[i];
        float2 f0 = __half22float2(*(const __half2*)&tw[(size_t)__float_as_int(p0.x) * Cn + 2 * c]);
        ax = fmaf(p0.y, f0.x, ax);
        ay = fmaf(p0.y, f0.y, ay);
    }

    ax += __shfl_xor(ax, 32);
    ay += __shfl_xor(ay, 32);

    if (hgrp == 0) {
        const float2 bv = *(const float2*)&b[w * Cn + 2 * c];
        float vx = elu_f(ax + bv.x);
        float vy = elu_f(ay + bv.y);
        const size_t oi = ((size_t)w * Nn + d) * Cn + 2 * c;
        if (LAST) {
            const float2 xv = *(const float2*)&x[oi];
            vx += xv.x;
            vy += xv.y;
        }
        *(float2*)&out[oi] = make_float2(vx, vy);
    }
}

// ---------------------------------------------------------------------------
// ws layout (floats):
//   [0)          pairs : 7,680,000
//   [7,680,000)  offs  :   240,384 (int)  -- written by bucketB now
//   [7,920,384)  bcur  :   240,000 (int)  -- [0,960) counts, [1024,1984) bases
//   [8,160,384)  wTreg :   240,000 (int)  -- wT (32768 halfs)
//   [8,400,384)  H     : 15,360,000      -- doubles as bstr (35.4 MB) before
//                                           inception overwrites it (in-order)
// t (fp16) lives in d_out between matmul and agg; final result built in H,
// then copied to d_out.
// ---------------------------------------------------------------------------
extern "C" void kernel_launch(void* const* d_in, const int* in_sizes, int n_in,
                              void* d_out, int out_size, void* d_ws, size_t ws_size,
                              hipStream_t stream)
{
    const float* x    = (const float*)d_in[0];
    const int*   ei   = (const int*)d_in[1];
    const float* ew   = (const float*)d_in[2];
    const float* sw1  = (const float*)d_in[3];
    const float* sb1  = (const float*)d_in[4];
    const float* gw1  = (const float*)d_in[5];
    const float* gb1  = (const float*)d_in[6];
    const float* sw3  = (const float*)d_in[7];
    const float* sb3  = (const float*)d_in[8];
    const float* gw3  = (const float*)d_in[9];
    const float* gb3  = (const float*)d_in[10];
    const float* sw5  = (const float*)d_in[11];
    const float* sb5  = (const float*)d_in[12];
    const float* gw5  = (const float*)d_in[13];
    const float* gb5  = (const float*)d_in[14];
    const float* sw7  = (const float*)d_in[15];
    const float* sb7  = (const float*)d_in[16];
    const float* gw7  = (const float*)d_in[17];
    const float* gb7  = (const float*)d_in[18];
    const float* gcnw = (const float*)d_in[19];
    const float* gcnb = (const float*)d_in[20];
    float* out = (float*)d_out;
    __half* Th = (__half*)d_out;

    const size_t WNC = (size_t)Wn * Nn * Cn;
    const int mm_grid = (Nn + 63) / 64;    // 313 — tail block guarded

    float2* pairs = (float2*)d_ws;
    int*    offs  = (int*)((float*)d_ws + 7680000);
    int*    bcur  = offs + 240384;
    int*    bbase = bcur + 1024;
    __half* wT    = (__half*)(bcur + 240000);
    float*  H     = (float*)((int*)wT + 240000);
    uint2*  bstr  = (uint2*)H;             // phase-A bucket streams (dead after B)

    // --- sort preamble (no global per-dst histogram: scattered atomics cost
    //     ~31 B HBM write each; bucket counts + local sort replace it) ---
    hipMemsetAsync(bcur, 0, (size_t)Wn * 80 * sizeof(int), stream);
    bucketA_kernel<<<dim3(En / 2560, Wn), 256, 0, stream>>>(ei, ew, bcur, bstr);
    bscan_kernel<<<1, 768, 0, stream>>>(bcur, bbase);
    bucketB_kernel<<<dim3(NBKT, Wn), 256, 0, stream>>>(bstr, bcur, bbase, offs, pairs);

    // --- weight fragment pack (fp16) ---
    wprep_kernel<<<128, 256, 0, stream>>>(sw1, gw1, sw3, gw3, sw5, gw5, sw7, gw7, wT);

    // --- feature path (MFMA) ---
    inception_mfma_kernel<<<Nn / 16, 256, 0, stream>>>(
        x, sb1, gb1, sb3, gb3, sb5, gb5, sb7, gb7, wT, H);

    // hop 0
    matmul_half_kernel<<<dim3(mm_grid, Wn), 256, 0, stream>>>(H, gcnw, Th);
    agg_kernel<false><<<60000, 256, 0, stream>>>(
        Th, pairs, offs, gcnb, nullptr, H);

    // hop 1
    matmul_half_kernel<<<dim3(mm_grid, Wn), 256, 0, stream>>>(
        H, gcnw + (size_t)Wn * Cn * Cn, Th);
    agg_kernel<true><<<60000, 256, 0, stream>>>(
        Th, pairs, offs, gcnb + (size_t)Wn * Cn, x, H);
    hipMemcpyAsync(out, H, WNC * sizeof(float), hipMemcpyDeviceToDevice, stream);
}

// Round 7
// 661.213 us; speedup vs baseline: 1.6831x; 1.0781x over previous
//
#include <hip/hip_runtime.h>
#include <hip/hip_fp16.h>
#include <cstddef>

#define Wn 12
#define Nn 20000
#define Cn 64
#define En 320000
#define OFFS_STRIDE 20032
#define NBKT 79
#define BCAP 4672

typedef _Float16 h4v __attribute__((ext_vector_type(4)));
typedef _Float16 h8v __attribute__((ext_vector_type(8)));
typedef float    f4v __attribute__((ext_vector_type(4)));

__device__ __forceinline__ float elu_f(float v) {
    return v > 0.f ? v : (expf(v) - 1.f);
}

// ---------------------------------------------------------------------------
// Weight prep: pack all 4 kernel sizes (sig+gate) into MFMA B-fragment order.
// ---------------------------------------------------------------------------
__global__ __launch_bounds__(256) void wprep_kernel(
    const float* __restrict__ sw1, const float* __restrict__ gw1,
    const float* __restrict__ sw3, const float* __restrict__ gw3,
    const float* __restrict__ sw5, const float* __restrict__ gw5,
    const float* __restrict__ sw7, const float* __restrict__ gw7,
    __half* __restrict__ dst)
{
    const int i = blockIdx.x * 256 + threadIdx.x;   // 32768 total
    if (i >= 32768) return;
    const int j    = i & 7;
    const int lane = (i >> 3) & 63;
    const int slot = i >> 9;                        // 0..63
    int g, loc;
    if (slot < 4)       { g = 0; loc = slot; }
    else if (slot < 16) { g = 1; loc = slot - 4; }
    else if (slot < 36) { g = 2; loc = slot - 16; }
    else                { g = 3; loc = slot - 36; }
    const int k   = 2 * g + 1;
    const int nks = 2 * k;                          // k-steps per path
    const int sg  = (loc >= nks) ? 1 : 0;          // 0 = sig, 1 = gate
    const int s   = loc - sg * nks;
    const int t   = s >> 1;                         // tap 0..k-1
    const int ih  = s & 1;                          // ic half
    const int oc  = lane & 15;
    const int ic  = ih * 32 + (lane >> 4) * 8 + j;
    const float* src;
    switch (g * 2 + sg) {
      case 0: src = sw1; break; case 1: src = gw1; break;
      case 2: src = sw3; break; case 3: src = gw3; break;
      case 4: src = sw5; break; case 5: src = gw5; break;
      case 6: src = sw7; break; default: src = gw7; break;
    }
    dst[i] = __float2half(src[(oc * 64 + ic) * k + t]);
}

// ---------------------------------------------------------------------------
// One oc-group of the inception conv via MFMA.
// ---------------------------------------------------------------------------
template<int G>
__device__ __forceinline__ void mfma_group(
    const __half* __restrict__ wTg,    // global fragment-packed weights, group G
    __half* __restrict__ wsh,
    const __half* __restrict__ xsh,
    const float* __restrict__ sb, const float* __restrict__ gb,
    float* __restrict__ h, int nb, int tid)
{
    constexpr int NKS = 2 * (2 * G + 1);
    {
        const uint4* src = (const uint4*)wTg;
        uint4* dst = (uint4*)wsh;
        #pragma unroll
        for (int i = 0; i < 2 * G + 1; ++i)
            dst[tid + i * 256] = src[tid + i * 256];
    }
    __syncthreads();

    const int lane = tid & 63;
    const int wv   = tid >> 6;                 // 0..3
    const int node16 = lane & 15;
    const int abase = node16 * 128;
    const int swz   = (lane & 7) << 4;
    const int aoff0 = abase + ((0  + (lane >> 4) * 16) ^ swz);
    const int aoff1 = abase + ((64 + (lane >> 4) * 16) ^ swz);

    f4v accS[3], accG[3];
    #pragma unroll
    for (int m = 0; m < 3; ++m) {
        accS[m] = (f4v){0.f, 0.f, 0.f, 0.f};
        accG[m] = (f4v){0.f, 0.f, 0.f, 0.f};
    }

    #pragma unroll
    for (int s2 = 0; s2 < 2 * G + 1; ++s2) {   // dw = s2 - G
        const int dw = s2 - G;
        #pragma unroll
        for (int ih = 0; ih < 2; ++ih) {
            const int s = s2 * 2 + ih;
            const h8v bs = *(const h8v*)&wsh[(s * 64 + lane) * 8];
            const h8v bg = *(const h8v*)&wsh[((NKS + s) * 64 + lane) * 8];
            const int laneoff = ih ? aoff1 : aoff0;
            #pragma unroll
            for (int m = 0; m < 3; ++m) {
                const int w  = wv * 3 + m;
                const int wp = w + dw;
                if (wp >= 0 && wp < Wn) {      // wave-uniform
                    const h8v a = *(const h8v*)((const char*)xsh + wp * 2048 + laneoff);
                    accS[m] = __builtin_amdgcn_mfma_f32_16x16x32_f16(a, bs, accS[m], 0, 0, 0);
                    accG[m] = __builtin_amdgcn_mfma_f32_16x16x32_f16(a, bg, accG[m], 0, 0, 0);
                }
            }
        }
    }

    const float sbv = sb[node16];
    const float gbv = gb[node16];
    const int oc = G * 16 + node16;
    #pragma unroll
    for (int m = 0; m < 3; ++m) {
        const int w = wv * 3 + m;
        #pragma unroll
        for (int r = 0; r < 4; ++r) {
            const int node = (lane >> 4) * 4 + r;
            const float sv = accS[m][r] + sbv;
            const float gv = accG[m][r] + gbv;
            const float rv = sv > 0.f ? sv : 0.f;
            const float sg = 1.f / (1.f + expf(-gv));
            h[((size_t)w * Nn + nb + node) * Cn + oc] = rv * sg;
        }
    }
    __syncthreads();   // wsh reused by next group
}

// ---------------------------------------------------------------------------
// Inception gated temporal conv, MFMA version.
// ---------------------------------------------------------------------------
__global__ __launch_bounds__(256, 3) void inception_mfma_kernel(
    const float* __restrict__ x,
    const float* __restrict__ sb1, const float* __restrict__ gb1,
    const float* __restrict__ sb3, const float* __restrict__ gb3,
    const float* __restrict__ sb5, const float* __restrict__ gb5,
    const float* __restrict__ sb7, const float* __restrict__ gb7,
    const __half* __restrict__ wT,
    float* __restrict__ h)
{
    __shared__ __align__(16) __half xsh[12 * 16 * 64];   // 24,576 B
    __shared__ __align__(16) __half wsh[14336];           // 28,672 B (max group)
    const int tid = threadIdx.x;
    const int nb  = blockIdx.x * 16;

    const float4* xg = (const float4*)x;
    for (int i = tid; i < 3072; i += 256) {
        const int w = i >> 8, r = i & 255, node = r >> 4, c4 = r & 15;
        const float4 v = xg[((size_t)w * Nn + nb + node) * 16 + c4];
        h4v p = { (_Float16)v.x, (_Float16)v.y, (_Float16)v.z, (_Float16)v.w };
        const int off = w * 2048 + node * 128 + (((c4 << 3)) ^ ((node & 7) << 4));
        *(h4v*)((char*)xsh + off) = p;
    }
    mfma_group<0>(wT,         wsh, xsh, sb1, gb1, h, nb, tid);
    mfma_group<1>(wT + 2048,  wsh, xsh, sb3, gb3, h, nb, tid);
    mfma_group<2>(wT + 8192,  wsh, xsh, sb5, gb5, h, nb, tid);
    mfma_group<3>(wT + 18432, wsh, xsh, sb7, gb7, h, nb, tid);
}

// ---------------------------------------------------------------------------
// Per-window (N x 64) @ (64 x 64) matmul, fp32 in -> fp16 out. Tail guarded.
// ---------------------------------------------------------------------------
__global__ __launch_bounds__(256) void matmul_half_kernel(
    const float* __restrict__ h, const float* __restrict__ gw,
    __half* __restrict__ t)
{
    const int w  = blockIdx.y;
    const int nb = blockIdx.x * 64;
    __shared__ float wm[64 * 64];
    __shared__ float hT[64 * 64];
    const int tid = threadIdx.x;

    const float4* wsrc = (const float4*)(gw + (size_t)w * 4096);
    float4* wm4 = (float4*)wm;
    for (int i = tid; i < 1024; i += 256) wm4[i] = wsrc[i];

    {
        const int n = tid >> 2, icq = tid & 3;
        const int nclamp = (nb + n < Nn) ? (nb + n) : (Nn - 1);
        const float4* hsrc = (const float4*)(h + ((size_t)w * Nn + nclamp) * 64);
        #pragma unroll
        for (int k = 0; k < 4; ++k) {
            float4 v = hsrc[icq + 4 * k];
            int ic = (icq + 4 * k) * 4;
            hT[(ic + 0) * 64 + n] = v.x;
            hT[(ic + 1) * 64 + n] = v.y;
            hT[(ic + 2) * 64 + n] = v.z;
            hT[(ic + 3) * 64 + n] = v.w;
        }
    }
    __syncthreads();

    const int oc0 = (tid & 15) * 4;
    const int n0  = (tid >> 4) * 4;
    float acc[4][4] = {{0.f}};
    #pragma unroll
    for (int ic = 0; ic < 64; ++ic) {
        const float4 hv = *(const float4*)&hT[ic * 64 + n0];
        const float4 wv = *(const float4*)&wm[ic * 64 + oc0];
        acc[0][0] = fmaf(hv.x, wv.x, acc[0][0]);
        acc[0][1] = fmaf(hv.x, wv.y, acc[0][1]);
        acc[0][2] = fmaf(hv.x, wv.z, acc[0][2]);
        acc[0][3] = fmaf(hv.x, wv.w, acc[0][3]);
        acc[1][0] = fmaf(hv.y, wv.x, acc[1][0]);
        acc[1][1] = fmaf(hv.y, wv.y, acc[1][1]);
        acc[1][2] = fmaf(hv.y, wv.z, acc[1][2]);
        acc[1][3] = fmaf(hv.y, wv.w, acc[1][3]);
        acc[2][0] = fmaf(hv.z, wv.x, acc[2][0]);
        acc[2][1] = fmaf(hv.z, wv.y, acc[2][1]);
        acc[2][2] = fmaf(hv.z, wv.z, acc[2][2]);
        acc[2][3] = fmaf(hv.z, wv.w, acc[2][3]);
        acc[3][0] = fmaf(hv.w, wv.x, acc[3][0]);
        acc[3][1] = fmaf(hv.w, wv.y, acc[3][1]);
        acc[3][2] = fmaf(hv.w, wv.z, acc[3][2]);
        acc[3][3] = fmaf(hv.w, wv.w, acc[3][3]);
    }

    #pragma unroll
    for (int i = 0; i < 4; ++i) {
        if (nb + n0 + i < Nn) {
            __half2 lo = __floats2half2_rn(acc[i][0], acc[i][1]);
            __half2 hi = __floats2half2_rn(acc[i][2], acc[i][3]);
            uint2 pack;
            pack.x = *(const unsigned int*)&lo;
            pack.y = *(const unsigned int*)&hi;
            *(uint2*)&t[((size_t)w * Nn + nb + n0 + i) * 64 + oc0] = pack;
        }
    }
}

// ---------------------------------------------------------------------------
// Bucketed sort, phase A: bin 2560 edges/block into 79 coarse dst-buckets
// (dst>>8). Edges are compacted bucket-contiguous in LDS, segments reserved
// with ONE global atomic per bucket, then flushed with consecutive-address
// runs -> line-granular HBM writes. Entry pack: src (16b) | dst&255
// (bits 16..23), weight bits in .y.
// ---------------------------------------------------------------------------
__global__ __launch_bounds__(256) void bucketA_kernel(
    const int* __restrict__ ei, const float* __restrict__ ew,
    int* __restrict__ bcur, uint2* __restrict__ bstr)
{
    const int w   = blockIdx.y;
    const int tid = threadIdx.x;
    __shared__ uint2 compact[2560];
    __shared__ unsigned char bkid[2560];
    __shared__ int rcnt[NBKT], rbase[NBKT], sbase[NBKT];
    __shared__ int sc[128];

    const int* eis = ei + (size_t)w * 2 * En;
    const float* ews = ew + (size_t)w * En;
    const int e0 = blockIdx.x * 2560;

    if (tid < NBKT) rcnt[tid] = 0;
    __syncthreads();

    int myb[10], myr[10];
    uint2 mye[10];
    #pragma unroll
    for (int it = 0; it < 10; ++it) {
        const int e = e0 + it * 256 + tid;
        const int s = eis[e];
        const int d = eis[En + e];
        const float wt = ews[e];
        const int bk = d >> 8;
        myb[it] = bk;
        mye[it].x = (unsigned)s | ((unsigned)(d & 255) << 16);
        mye[it].y = __float_as_uint(wt);
        myr[it] = atomicAdd(&rcnt[bk], 1);
    }
    __syncthreads();
    if (tid < 128) sc[tid] = (tid < NBKT) ? rcnt[tid] : 0;
    __syncthreads();
    #pragma unroll
    for (int dlt = 1; dlt < 128; dlt <<= 1) {
        int t = (tid < 128 && tid >= dlt) ? sc[tid - dlt] : 0;
        __syncthreads();
        if (tid < 128) sc[tid] += t;
        __syncthreads();
    }
    if (tid < NBKT) {
        rbase[tid] = sc[tid] - rcnt[tid];                       // excl within block
        sbase[tid] = atomicAdd(&bcur[w * 80 + tid], rcnt[tid]); // segment in stream
    }
    __syncthreads();
    #pragma unroll
    for (int it = 0; it < 10; ++it) {
        const int p = rbase[myb[it]] + myr[it];
        compact[p] = mye[it];
        bkid[p] = (unsigned char)myb[it];
    }
    __syncthreads();
    for (int i = tid; i < 2560; i += 256) {
        const int bk = bkid[i];
        int off = sbase[bk] + (i - rbase[bk]);
        if (off >= BCAP) off = BCAP - 1;   // ~9 sigma guard, never expected
        bstr[((size_t)w * NBKT + bk) * BCAP + off] = compact[i];
    }
}

// ---------------------------------------------------------------------------
// Tiny scan over the 12 x 79 bucket counts -> exclusive bucket bases.
// ---------------------------------------------------------------------------
__global__ __launch_bounds__(768) void bscan_kernel(
    const int* __restrict__ bcur, int* __restrict__ bbase)
{
    const int lane = threadIdx.x & 63;
    const int w    = threadIdx.x >> 6;   // 0..11
    const int c0 = (lane < NBKT) ? bcur[w * 80 + lane] : 0;
    int s = c0;
    #pragma unroll
    for (int d = 1; d < 64; d <<= 1) {
        int t = __shfl_up(s, d);
        if (lane >= d) s += t;
    }
    const int tot0 = __shfl(s, 63);
    const int c1 = (lane + 64 < NBKT) ? bcur[w * 80 + 64 + lane] : 0;
    int s1 = c1;
    #pragma unroll
    for (int d = 1; d < 64; d <<= 1) {
        int t = __shfl_up(s1, d);
        if (lane >= d) s1 += t;
    }
    s1 += tot0;
    bbase[w * 80 + lane] = s - c0;
    if (lane + 64 < NBKT) bbase[w * 80 + 64 + lane] = s1 - c1;
}

// ---------------------------------------------------------------------------
// Bucketed sort, phase B: counting-sort one bucket, emit pairs + CSR offs.
// ---------------------------------------------------------------------------
__global__ __launch_bounds__(256) void bucketB_kernel(
    const uint2* __restrict__ bstr, const int* __restrict__ bcur,
    const int* __restrict__ bbase, int* __restrict__ offs,
    float2* __restrict__ pairs)
{
    const int bk = blockIdx.x, w = blockIdx.y;
    const int tid = threadIdx.x;
    __shared__ uint2 sorted[BCAP];
    __shared__ int lhist[256], lbase[256], wsum[4];
    int n = bcur[w * 80 + bk];
    if (n > BCAP) n = BCAP;
    const int gbase = bbase[w * 80 + bk];
    const uint2* src = bstr + ((size_t)w * NBKT + bk) * BCAP;

    lhist[tid] = 0;
    __syncthreads();

    constexpr int MAXE = (BCAP + 255) / 256;   // 19
    uint2 mye[MAXE];
    short myd[MAXE], myr[MAXE];
    #pragma unroll
    for (int it = 0; it < MAXE; ++it) {
        const int i = tid + it * 256;
        if (i < n) {
            const uint2 e = src[i];
            mye[it] = e;
            const int dl = (e.x >> 16) & 255;
            myd[it] = (short)dl;
            myr[it] = (short)atomicAdd(&lhist[dl], 1);
        }
    }
    __syncthreads();
    {
        const int lane = tid & 63, wv = tid >> 6;
        const int v = lhist[tid];
        int sum = v;
        #pragma unroll
        for (int dlt = 1; dlt < 64; dlt <<= 1) {
            int t = __shfl_up(sum, dlt);
            if (lane >= dlt) sum += t;
        }
        if (lane == 63) wsum[wv] = sum;
        __syncthreads();
        if (tid < 4) {
            int o = wsum[tid], s2 = o;
            #pragma unroll
            for (int dlt = 1; dlt < 4; dlt <<= 1) {
                int t = __shfl_up(s2, dlt);
                if (tid >= dlt) s2 += t;
            }
            wsum[tid] = s2 - o;            // exclusive across waves
        }
        __syncthreads();
        const int be = wsum[wv] + sum - v; // exclusive per-dst base
        lbase[tid] = be;
        const int d = bk * 256 + tid;
        if (d < Nn) offs[w * OFFS_STRIDE + d] = gbase + be;
        if (bk == NBKT - 1 && tid == 0) offs[w * OFFS_STRIDE + Nn] = En;
    }
    __syncthreads();
    #pragma unroll
    for (int it = 0; it < MAXE; ++it) {
        const int i = tid + it * 256;
        if (i < n)
            sorted[lbase[myd[it]] + myr[it]] = mye[it];
    }
    __syncthreads();
    float2* pw = pairs + (size_t)w * En + gbase;
    for (int i = tid; i < n; i += 256) {
        const uint2 e = sorted[i];
        pw[i] = make_float2(__int_as_float((int)(e.x & 0xFFFFu)), __uint_as_float(e.y));
    }
}

// ---------------------------------------------------------------------------
// Aggregation v3: 16 lanes/edge x 4 edge-subgroups, 4 channels/lane (8 B
// dwordx2 gather), unroll x2 -> 8 edges in flight per wave. Halves VALU
// instructions per edge vs the half2 form (round-6 counters: VALUBusy 47%,
// HBM 13% -> issue/latency-bound, not BW-bound). Cross-subgroup reduce =
// 2 shfl_xor rounds; eg==0 lanes do bias/ELU/residual + float4 store.
// XCD-affinity swizzle unchanged.
// ---------------------------------------------------------------------------
template<bool LAST>
__global__ __launch_bounds__(256) void agg_kernel(
    const __half* __restrict__ t, const float2* __restrict__ pairs,
    const int* __restrict__ offs, const float* __restrict__ b,
    const float* __restrict__ x, float* __restrict__ out)
{
    const int blk = blockIdx.x;
    const int r = blk & 7, q = blk >> 3;
    int w, ng;
    if (q < 5000) { w = r; ng = q; }
    else { int q2 = q - 5000; w = 8 + (r >> 1); ng = q2 * 2 + (r & 1); }

    const int d    = ng * 4 + (threadIdx.x >> 6);
    const int lane = threadIdx.x & 63;
    const int eg   = lane >> 4;           // edge subgroup 0..3
    const int c4   = lane & 15;           // channel quad (4 channels)
    const int* ow  = offs + w * OFFS_STRIDE;
    const int beg = ow[d];
    const int end = ow[d + 1];
    const float2* pw = pairs + (size_t)w * En;
    const __half* tw = t + (size_t)w * Nn * Cn;

    float a0 = 0.f, a1 = 0.f, a2 = 0.f, a3 = 0.f;
    int i = beg;
    for (; i + 8 <= end; i += 8) {
        const float2 pA = pw[i + eg];
        const float2 pB = pw[i + 4 + eg];
        const uint2 rA = *(const uint2*)&tw[(size_t)__float_as_int(pA.x) * Cn + c4 * 4];
        const uint2 rB = *(const uint2*)&tw[(size_t)__float_as_int(pB.x) * Cn + c4 * 4];
        const float2 fa01 = __half22float2(*(const __half2*)&rA.x);
        const float2 fa23 = __half22float2(*(const __half2*)&rA.y);
        const float2 fb01 = __half22float2(*(const __half2*)&rB.x);
        const float2 fb23 = __half22float2(*(const __half2*)&rB.y);
        a0 = fmaf(pA.y, fa01.x, a0);
        a1 = fmaf(pA.y, fa01.y, a1);
        a2 = fmaf(pA.y, fa23.x, a2);
        a3 = fmaf(pA.y, fa23.y, a3);
        a0 = fmaf(pB.y, fb01.x, a0);
        a1 = fmaf(pB.y, fb01.y, a1);
        a2 = fmaf(pB.y, fb23.x, a2);
        a3 = fmaf(pB.y, fb23.y, a3);
    }
    if (i + 4 <= end) {
        const float2 pA = pw[i + eg];
        const uint2 rA = *(const uint2*)&tw[(size_t)__float_as_int(pA.x) * Cn + c4 * 4];
        const float2 fa01 = __half22float2(*(const __half2*)&rA.x);
        const float2 fa23 = __half22float2(*(const __half2*)&rA.y);
        a0 = fmaf(pA.y, fa01.x, a0);
        a1 = fmaf(pA.y, fa01.y, a1);
        a2 = fmaf(pA.y, fa23.x, a2);
        a3 = fmaf(pA.y, fa23.y, a3);
        i += 4;
    }
    if (i + eg < end) {
        const float2 pA = pw[i + eg];
        const uint2 rA = *(const uint2*)&tw[(size_t)__float_as_int(pA.x) * Cn + c4 * 4];
        const float2 fa01 = __half22float2(*(const __half2*)&rA.x);
        const float2 fa23 = __half22float2(*(const __half2*)&rA.y);
        a0 = fmaf(pA.y, fa01.x, a0);
        a1 = fmaf(pA.y, fa01.y, a1);
        a2 = fmaf(pA.y, fa23.x, a2);
        a3 = fmaf(pA.y, fa23.y, a3);
    }

    a0 += __shfl_xor(a0, 16); a0 += __shfl_xor(a0, 32);
    a1 += __shfl_xor(a1, 16); a1 += __shfl_xor(a1, 32);
    a2 += __shfl_xor(a2, 16); a2 += __shfl_xor(a2, 32);
    a3 += __shfl_xor(a3, 16); a3 += __shfl_xor(a3, 32);

    if (eg == 0) {
        const float4 bv = *(const float4*)&b[w * Cn + c4 * 4];
        float v0 = elu_f(a0 + bv.x);
        float v1 = elu_f(a1 + bv.y);
        float v2 = elu_f(a2 + bv.z);
        float v3 = elu_f(a3 + bv.w);
        const size_t oi = ((size_t)w * Nn + d) * Cn + c4 * 4;
        if (LAST) {
            const float4 xv = *(const float4*)&x[oi];
            v0 += xv.x; v1 += xv.y; v2 += xv.z; v3 += xv.w;
        }
        *(float4*)&out[oi] = make_float4(v0, v1, v2, v3);
    }
}

// ---------------------------------------------------------------------------
// ws layout (floats):
//   [0)          pairs : 7,680,000
//   [7,680,000)  offs  :   240,384 (int)  -- written by bucketB
//   [7,920,384)  bcur  :   240,000 (int)  -- [0,960) counts, [1024,1984) bases
//   [8,160,384)  wTreg :   240,000 (int)  -- wT (32768 halfs)
//   [8,400,384)  H     : 15,360,000      -- doubles as bstr (35.4 MB) before
//                                           inception overwrites it (in-order)
// ---------------------------------------------------------------------------
extern "C" void kernel_launch(void* const* d_in, const int* in_sizes, int n_in,
                              void* d_out, int out_size, void* d_ws, size_t ws_size,
                              hipStream_t stream)
{
    const float* x    = (const float*)d_in[0];
    const int*   ei   = (const int*)d_in[1];
    const float* ew   = (const float*)d_in[2];
    const float* sw1  = (const float*)d_in[3];
    const float* sb1  = (const float*)d_in[4];
    const float* gw1  = (const float*)d_in[5];
    const float* gb1  = (const float*)d_in[6];
    const float* sw3  = (const float*)d_in[7];
    const float* sb3  = (const float*)d_in[8];
    const float* gw3  = (const float*)d_in[9];
    const float* gb3  = (const float*)d_in[10];
    const float* sw5  = (const float*)d_in[11];
    const float* sb5  = (const float*)d_in[12];
    const float* gw5  = (const float*)d_in[13];
    const float* gb5  = (const float*)d_in[14];
    const float* sw7  = (const float*)d_in[15];
    const float* sb7  = (const float*)d_in[16];
    const float* gw7  = (const float*)d_in[17];
    const float* gb7  = (const float*)d_in[18];
    const float* gcnw = (const float*)d_in[19];
    const float* gcnb = (const float*)d_in[20];
    float* out = (float*)d_out;
    __half* Th = (__half*)d_out;

    const size_t WNC = (size_t)Wn * Nn * Cn;
    const int mm_grid = (Nn + 63) / 64;    // 313 — tail block guarded

    float2* pairs = (float2*)d_ws;
    int*    offs  = (int*)((float*)d_ws + 7680000);
    int*    bcur  = offs + 240384;
    int*    bbase = bcur + 1024;
    __half* wT    = (__half*)(bcur + 240000);
    float*  H     = (float*)((int*)wT + 240000);
    uint2*  bstr  = (uint2*)H;             // phase-A bucket streams (dead after B)

    // --- sort preamble ---
    hipMemsetAsync(bcur, 0, (size_t)Wn * 80 * sizeof(int), stream);
    bucketA_kernel<<<dim3(En / 2560, Wn), 256, 0, stream>>>(ei, ew, bcur, bstr);
    bscan_kernel<<<1, 768, 0, stream>>>(bcur, bbase);
    bucketB_kernel<<<dim3(NBKT, Wn), 256, 0, stream>>>(bstr, bcur, bbase, offs, pairs);

    // --- weight fragment pack (fp16) ---
    wprep_kernel<<<128, 256, 0, stream>>>(sw1, gw1, sw3, gw3, sw5, gw5, sw7, gw7, wT);

    // --- feature path (MFMA) ---
    inception_mfma_kernel<<<Nn / 16, 256, 0, stream>>>(
        x, sb1, gb1, sb3, gb3, sb5, gb5, sb7, gb7, wT, H);

    // hop 0
    matmul_half_kernel<<<dim3(mm_grid, Wn), 256, 0, stream>>>(H, gcnw, Th);
    agg_kernel<false><<<60000, 256, 0, stream>>>(
        Th, pairs, offs, gcnb, nullptr, H);

    // hop 1
    matmul_half_kernel<<<dim3(mm_grid, Wn), 256, 0, stream>>>(
        H, gcnw + (size_t)Wn * Cn * Cn, Th);
    agg_kernel<true><<<60000, 256, 0, stream>>>(
        Th, pairs, offs, gcnb + (size_t)Wn * Cn, x, H);
    hipMemcpyAsync(out, H, WNC * sizeof(float), hipMemcpyDeviceToDevice, stream);
}